// Round 10
// baseline (345.757 us; speedup 1.0000x reference)
//
#include <hip/hip_runtime.h>
#include <math.h>

typedef unsigned short ushort_t;
typedef unsigned int uint_t;

// Problem constants
#define B_      8
#define T_      2048
#define DIMX    512
#define DM      128
#define DINNER  256
#define NSTATE  16
#define HDIM    64
#define NH      4
#define CONVDIM 288
#define PROJ    548
#define KCONV   4
#define LLAYERS 2
#define QCH     128
#define NC      (T_/QCH)
#define EPSF    1e-5f
#define MTOK    (B_*T_)

// ---- workspace layout (float offsets) ----
#define OFF_H      0u
#define OFF_HNB    4000000u    // ushort[MTOK*128] pre-normed bf16 h (free ex-proj region)
#define OFF_Z      20119552u
#define OFF_DEC    21168128u
#define OFF_PART   21168640u   // float[256*128] final-norm partial pools
#define OFF_WTIN   23396864u
#define OFF_WTINP  23429632u
#define OFF_WTOUT  23503360u
#define OFF_PROJB  23600000u   // ushort[MTOK*544]
#define OFF_DTRAW  28100000u   // float [MTOK*4]
#define OFF_YB     30600000u   // ushort[MTOK*256]

__device__ __forceinline__ ushort_t f2b(float f) {
    uint_t u = __builtin_bit_cast(uint_t, f);
    return (ushort_t)((u + 0x7FFFu + ((u >> 16) & 1u)) >> 16);
}
__device__ __forceinline__ float b2f(ushort_t b) {
    uint_t u = ((uint_t)b) << 16;
    return __builtin_bit_cast(float, u);
}
__device__ __forceinline__ float blo(uint_t u) { return b2f((ushort_t)(u & 0xffffu)); }
__device__ __forceinline__ float bhi(uint_t u) { return b2f((ushort_t)(u >> 16)); }

typedef short bf8 __attribute__((ext_vector_type(8)));
typedef float f4v __attribute__((ext_vector_type(4)));

// ===== all weight transposes in ONE kernel (proven r8) =====
__global__ __launch_bounds__(256) void k_wt_all(
    const float* __restrict__ in_w, const float* __restrict__ inproj_w,
    const float* __restrict__ outproj_w,
    ushort_t* __restrict__ wt_in, ushort_t* __restrict__ wt_inp,
    ushort_t* __restrict__ wt_out)
{
    __shared__ float tile[64][65];
    int idx = blockIdx.x;
    const float* W; ushort_t* Wt; int K, N, k0, n0;
    if (idx < 16) {
        W = in_w; Wt = wt_in; K = 512; N = 128;
        k0 = (idx & 7) * 64; n0 = (idx >> 3) * 64;
    } else if (idx < 52) {
        int r = idx - 16; int l = r / 18; r -= l * 18;
        W = inproj_w + l * 128 * PROJ; Wt = wt_inp + l * 576 * 128; K = 128; N = PROJ;
        k0 = (r & 1) * 64; n0 = (r >> 1) * 64;
    } else {
        int r = idx - 52; int l = r / 8; r -= l * 8;
        W = outproj_w + l * 256 * 128; Wt = wt_out + l * 128 * 256; K = 256; N = 128;
        k0 = (r & 3) * 64; n0 = (r >> 2) * 64;
    }
    const int tid = threadIdx.x;
#pragma unroll
    for (int it = 0; it < 16; ++it) {
        const int e = it * 256 + tid;
        const int kk = e >> 6, nn = e & 63;
        tile[kk][nn] = (n0 + nn < N) ? W[(k0 + kk) * N + (n0 + nn)] : 0.f;
    }
    __syncthreads();
#pragma unroll
    for (int it = 0; it < 16; ++it) {
        const int e = it * 256 + tid;
        const int nn = e >> 6, kk = e & 63;
        Wt[(n0 + nn) * K + k0 + kk] = f2b(tile[kk][nn]);
    }
}

// ===== input GEMM, n-tile paired (r9) + fused rmsnorm(layer0) epilogue (r10).
// hls aliases the dead Als/Bls staging (stride 136 floats, 16B-aligned rows);
// norm uses the EXACT r4 mapping/tree/pack -> hnb bits identical to old rms.
__global__ __launch_bounds__(256) void k_gemm_in(
    const float* __restrict__ x, const ushort_t* __restrict__ Bt,
    const float* __restrict__ ib, const float* __restrict__ nw,
    float* __restrict__ C, ushort_t* __restrict__ hnb)
{
    __shared__ ushort_t sm[64 * 136 * 2];   // Als | Bls ; epilogue: hls (fp32, stride 136)
    ushort_t* Als = sm;
    ushort_t* Bls = sm + 64 * 136;
    float* hls = (float*)sm;                // 64*136 floats = 34816 B = sizeof(sm)
    const int m0 = blockIdx.x * 64;
    const int tid = threadIdx.x;
    const int lane = tid & 63, w = tid >> 6;
    const int wm = (w >> 1) * 32, wn = (w & 1) * 32;
    const int r16 = lane & 15, q8 = (lane >> 4) * 8;
    const int q4 = (lane >> 4) * 4;

    f4v acc[2][2][2];   // [half][i][j]
#pragma unroll
    for (int hf = 0; hf < 2; ++hf)
#pragma unroll
        for (int i = 0; i < 2; ++i)
#pragma unroll
            for (int j = 0; j < 2; ++j) acc[hf][i][j] = (f4v)0.f;

    for (int kc = 0; kc < 512; kc += 128) {
#pragma unroll
        for (int i = 0; i < 4; ++i) {
            const int e = i * 2048 + tid * 8;
            const int r = e >> 7, c = e & 127;
            const float4 f0 = *(const float4*)&x[(m0 + r) * 512 + kc + c];
            const float4 f1 = *(const float4*)&x[(m0 + r) * 512 + kc + c + 4];
            uint4 pk;
            pk.x = (uint_t)f2b(f0.x) | ((uint_t)f2b(f0.y) << 16);
            pk.y = (uint_t)f2b(f0.z) | ((uint_t)f2b(f0.w) << 16);
            pk.z = (uint_t)f2b(f1.x) | ((uint_t)f2b(f1.y) << 16);
            pk.w = (uint_t)f2b(f1.z) | ((uint_t)f2b(f1.w) << 16);
            *(uint4*)&Als[r * 136 + c] = pk;
        }
#pragma unroll
        for (int hf = 0; hf < 2; ++hf) {
            const int n0 = hf * 64;
#pragma unroll
            for (int i = 0; i < 4; ++i) {
                const int e = i * 2048 + tid * 8;
                const int r = e >> 7, c = e & 127;
                *(uint4*)&Bls[r * 136 + c] = *(const uint4*)&Bt[(n0 + r) * 512 + kc + c];
            }
            __syncthreads();
#pragma unroll
            for (int kk = 0; kk < 128; kk += 32) {
                const bf8 a0 = *(const bf8*)&Als[(wm + r16) * 136 + kk + q8];
                const bf8 a1 = *(const bf8*)&Als[(wm + 16 + r16) * 136 + kk + q8];
                const bf8 b0 = *(const bf8*)&Bls[(wn + r16) * 136 + kk + q8];
                const bf8 b1 = *(const bf8*)&Bls[(wn + 16 + r16) * 136 + kk + q8];
                acc[hf][0][0] = __builtin_amdgcn_mfma_f32_16x16x32_bf16(a0, b0, acc[hf][0][0], 0, 0, 0);
                acc[hf][0][1] = __builtin_amdgcn_mfma_f32_16x16x32_bf16(a0, b1, acc[hf][0][1], 0, 0, 0);
                acc[hf][1][0] = __builtin_amdgcn_mfma_f32_16x16x32_bf16(a1, b0, acc[hf][1][0], 0, 0, 0);
                acc[hf][1][1] = __builtin_amdgcn_mfma_f32_16x16x32_bf16(a1, b1, acc[hf][1][1], 0, 0, 0);
            }
            __syncthreads();
        }
    }
    // epilogue: h = acc + bias -> global h + LDS hls
#pragma unroll
    for (int hf = 0; hf < 2; ++hf)
#pragma unroll
        for (int i = 0; i < 2; ++i)
#pragma unroll
            for (int j = 0; j < 2; ++j)
#pragma unroll
                for (int r = 0; r < 4; ++r) {
                    const int lr = wm + i * 16 + q4 + r;
                    const int gcol = hf * 64 + wn + j * 16 + r16;
                    const float v = acc[hf][i][j][r] + ib[gcol];
                    C[(m0 + lr) * 128 + gcol] = v;
                    hls[lr * 136 + gcol] = v;
                }
    __syncthreads();
    // rmsnorm (layer 0) -> hnb, exact r4 mapping
#pragma unroll
    for (int i = 0; i < 4; ++i) {
        const int e = i * 2048 + tid * 8;
        const int r = e >> 7, c = e & 127;
        const float4 f0 = *(const float4*)&hls[r * 136 + c];
        const float4 f1 = *(const float4*)&hls[r * 136 + c + 4];
        float ss = f0.x * f0.x + f0.y * f0.y + f0.z * f0.z + f0.w * f0.w
                 + f1.x * f1.x + f1.y * f1.y + f1.z * f1.z + f1.w * f1.w;
#pragma unroll
        for (int off = 1; off < 16; off <<= 1) ss += __shfl_xor(ss, off);
        const float rs = rsqrtf(ss * (1.f / 128.f) + EPSF);
        const float4 w0 = *(const float4*)&nw[c];
        const float4 w1 = *(const float4*)&nw[c + 4];
        uint4 pk;
        pk.x = (uint_t)f2b(f0.x * rs * w0.x) | ((uint_t)f2b(f0.y * rs * w0.y) << 16);
        pk.y = (uint_t)f2b(f0.z * rs * w0.z) | ((uint_t)f2b(f0.w * rs * w0.w) << 16);
        pk.z = (uint_t)f2b(f1.x * rs * w1.x) | ((uint_t)f2b(f1.y * rs * w1.y) << 16);
        pk.w = (uint_t)f2b(f1.z * rs * w1.z) | ((uint_t)f2b(f1.w * rs * w1.w) << 16);
        *(uint4*)&hnb[(m0 + r) * 128 + c] = pk;
    }
}

// ===== inproj GEMM, A = pre-normed bf16 hnb (r10) — norm phase removed;
// n-tile pairing kept (r8). Downstream bits identical to r9. =====
__global__ __launch_bounds__(256) void k_gemm_rms(
    const ushort_t* __restrict__ hnb,
    const ushort_t* __restrict__ Bt, ushort_t* __restrict__ projb,
    float* __restrict__ dtraw)
{
    __shared__ ushort_t Als[64 * 136];
    __shared__ ushort_t Bls[64 * 136];
    const int m0 = blockIdx.x * 64;
    const int tid = threadIdx.x;
    const int lane = tid & 63, w = tid >> 6;
    const int wm = (w >> 1) * 32, wn = (w & 1) * 32;
    const int r16 = lane & 15, q8 = (lane >> 4) * 8;
    const int q4 = (lane >> 4) * 4;

#pragma unroll
    for (int i = 0; i < 4; ++i) {
        const int e = i * 2048 + tid * 8;
        const int r = e >> 7, c = e & 127;
        *(uint4*)&Als[r * 136 + c] = *(const uint4*)&hnb[(m0 + r) * 128 + c];
    }

#pragma unroll
    for (int half = 0; half < 2; ++half) {
        const int n0 = blockIdx.y * 128 + half * 64;
        if (n0 >= 576) break;   // phantom tile at pair 4
#pragma unroll
        for (int i = 0; i < 4; ++i) {
            const int e = i * 2048 + tid * 8;
            const int r = e >> 7, c = e & 127;
            *(uint4*)&Bls[r * 136 + c] = *(const uint4*)&Bt[(n0 + r) * 128 + c];
        }
        __syncthreads();

        f4v acc[2][2];
#pragma unroll
        for (int i = 0; i < 2; ++i)
#pragma unroll
            for (int j = 0; j < 2; ++j) acc[i][j] = (f4v)0.f;
#pragma unroll
        for (int kk = 0; kk < 128; kk += 32) {
            const bf8 a0 = *(const bf8*)&Als[(wm + r16) * 136 + kk + q8];
            const bf8 a1 = *(const bf8*)&Als[(wm + 16 + r16) * 136 + kk + q8];
            const bf8 b0 = *(const bf8*)&Bls[(wn + r16) * 136 + kk + q8];
            const bf8 b1 = *(const bf8*)&Bls[(wn + 16 + r16) * 136 + kk + q8];
            acc[0][0] = __builtin_amdgcn_mfma_f32_16x16x32_bf16(a0, b0, acc[0][0], 0, 0, 0);
            acc[0][1] = __builtin_amdgcn_mfma_f32_16x16x32_bf16(a0, b1, acc[0][1], 0, 0, 0);
            acc[1][0] = __builtin_amdgcn_mfma_f32_16x16x32_bf16(a1, b0, acc[1][0], 0, 0, 0);
            acc[1][1] = __builtin_amdgcn_mfma_f32_16x16x32_bf16(a1, b1, acc[1][1], 0, 0, 0);
        }
        __syncthreads();   // protect Bls before restage (half 1)

#pragma unroll
        for (int i = 0; i < 2; ++i)
#pragma unroll
            for (int j = 0; j < 2; ++j)
#pragma unroll
                for (int r = 0; r < 4; ++r) {
                    const int grow = m0 + wm + i * 16 + q4 + r;
                    const int gcol = n0 + wn + j * 16 + r16;
                    if (gcol < 544) projb[grow * 544 + gcol] = f2b(acc[i][j][r]);
                    else if (gcol < PROJ) dtraw[grow * 4 + (gcol - 544)] = acc[i][j][r];
                }
    }
}

// ===== outproj GEMM + gated-RMSNorm, both halves in registers + fused tail (r10).
// MODE 0: write h, emit next-layer rmsnorm -> hnb (bit-identical to old path).
// MODE 1: skip h write; fused final-rmsnorm + partial mean-pool -> part.
template<int MODE>
__global__ __launch_bounds__(256) void k_gemm_gn(
    const ushort_t* __restrict__ yb, const ushort_t* __restrict__ projb,
    const float* __restrict__ gw, const ushort_t* __restrict__ Bt,
    float* __restrict__ C, const float* __restrict__ nw2,
    ushort_t* __restrict__ hnb, float* __restrict__ part)
{
    __shared__ ushort_t sm[64 * 264 + 64 * 136];  // Als264 | Bls136 ; tail: hls fp32
    __shared__ float rstd[64];
    __shared__ float padd[256];
    ushort_t* Als = sm;
    ushort_t* Bls = sm + 64 * 264;
    float* hls = (float*)sm;    // 64*136 floats = 34816 B <= 51200 B
    const int m0 = blockIdx.x * 64;
    const int tid = threadIdx.x;
    const int lane = tid & 63, w = tid >> 6;
    const int wm = (w >> 1) * 32, wn = (w & 1) * 32;
    const int r16 = lane & 15, q8 = (lane >> 4) * 8;
    const int q4 = (lane >> 4) * 4;

    // A staging + inline gated rmsnorm (once)
#pragma unroll
    for (int i = 0; i < 8; ++i) {
        const int e = i * 2048 + tid * 8;
        const int r = e >> 8, c = e & 255;
        const uint4 yv = *(const uint4*)&yb[(m0 + r) * 256 + c];
        const uint4 gv = *(const uint4*)&projb[(m0 + r) * 544 + c];
        const float g0 = blo(gv.x), g1 = bhi(gv.x), g2 = blo(gv.y), g3 = bhi(gv.y);
        const float g4 = blo(gv.z), g5 = bhi(gv.z), g6 = blo(gv.w), g7 = bhi(gv.w);
        float v0 = blo(yv.x) * (g0 / (1.f + __expf(-g0)));
        float v1 = bhi(yv.x) * (g1 / (1.f + __expf(-g1)));
        float v2 = blo(yv.y) * (g2 / (1.f + __expf(-g2)));
        float v3 = bhi(yv.y) * (g3 / (1.f + __expf(-g3)));
        float v4 = blo(yv.z) * (g4 / (1.f + __expf(-g4)));
        float v5 = bhi(yv.z) * (g5 / (1.f + __expf(-g5)));
        float v6 = blo(yv.w) * (g6 / (1.f + __expf(-g6)));
        float v7 = bhi(yv.w) * (g7 / (1.f + __expf(-g7)));
        float ss = v0 * v0 + v1 * v1 + v2 * v2 + v3 * v3
                 + v4 * v4 + v5 * v5 + v6 * v6 + v7 * v7;
#pragma unroll
        for (int off = 1; off < 32; off <<= 1) ss += __shfl_xor(ss, off);
        const float rs = rsqrtf(ss * (1.f / 256.f) + EPSF);
        const float4 w0 = *(const float4*)&gw[c];
        const float4 w1 = *(const float4*)&gw[c + 4];
        uint4 pk;
        pk.x = (uint_t)f2b(v0 * rs * w0.x) | ((uint_t)f2b(v1 * rs * w0.y) << 16);
        pk.y = (uint_t)f2b(v2 * rs * w0.z) | ((uint_t)f2b(v3 * rs * w0.w) << 16);
        pk.z = (uint_t)f2b(v4 * rs * w1.x) | ((uint_t)f2b(v5 * rs * w1.y) << 16);
        pk.w = (uint_t)f2b(v6 * rs * w1.z) | ((uint_t)f2b(v7 * rs * w1.w) << 16);
        *(uint4*)&Als[r * 264 + c] = pk;
    }

    f4v acc[2][2][2];   // [half][i][j]
#pragma unroll
    for (int hf = 0; hf < 2; ++hf)
#pragma unroll
        for (int i = 0; i < 2; ++i)
#pragma unroll
            for (int j = 0; j < 2; ++j) acc[hf][i][j] = (f4v)0.f;

#pragma unroll
    for (int hf = 0; hf < 2; ++hf) {
        const int n0 = hf * 64;
        for (int kc = 0; kc < 256; kc += 128) {
#pragma unroll
            for (int i = 0; i < 4; ++i) {
                const int e = i * 2048 + tid * 8;
                const int r = e >> 7, c = e & 127;
                *(uint4*)&Bls[r * 136 + c] = *(const uint4*)&Bt[(n0 + r) * 256 + kc + c];
            }
            __syncthreads();
#pragma unroll
            for (int kk = 0; kk < 128; kk += 32) {
                const bf8 a0 = *(const bf8*)&Als[(wm + r16) * 264 + kc + kk + q8];
                const bf8 a1 = *(const bf8*)&Als[(wm + 16 + r16) * 264 + kc + kk + q8];
                const bf8 b0 = *(const bf8*)&Bls[(wn + r16) * 136 + kk + q8];
                const bf8 b1 = *(const bf8*)&Bls[(wn + 16 + r16) * 136 + kk + q8];
                acc[hf][0][0] = __builtin_amdgcn_mfma_f32_16x16x32_bf16(a0, b0, acc[hf][0][0], 0, 0, 0);
                acc[hf][0][1] = __builtin_amdgcn_mfma_f32_16x16x32_bf16(a0, b1, acc[hf][0][1], 0, 0, 0);
                acc[hf][1][0] = __builtin_amdgcn_mfma_f32_16x16x32_bf16(a1, b0, acc[hf][1][0], 0, 0, 0);
                acc[hf][1][1] = __builtin_amdgcn_mfma_f32_16x16x32_bf16(a1, b1, acc[hf][1][1], 0, 0, 0);
            }
            __syncthreads();   // also guards Als alias below (all MFMA done)
        }
    }

    // epilogue: h = residual + acc -> (MODE0: global h) + LDS hls (aliases Als)
#pragma unroll
    for (int hf = 0; hf < 2; ++hf)
#pragma unroll
        for (int i = 0; i < 2; ++i)
#pragma unroll
            for (int j = 0; j < 2; ++j)
#pragma unroll
                for (int r = 0; r < 4; ++r) {
                    const int lr = wm + i * 16 + q4 + r;
                    const int gcol = hf * 64 + wn + j * 16 + r16;
                    const float v = acc[hf][i][j][r] + C[(m0 + lr) * 128 + gcol];
                    if (MODE == 0) C[(m0 + lr) * 128 + gcol] = v;
                    hls[lr * 136 + gcol] = v;
                }
    __syncthreads();

    if (MODE == 0) {
        // next-layer rmsnorm -> hnb (exact r4 mapping; bits identical to old)
#pragma unroll
        for (int i = 0; i < 4; ++i) {
            const int e = i * 2048 + tid * 8;
            const int r = e >> 7, c = e & 127;
            const float4 f0 = *(const float4*)&hls[r * 136 + c];
            const float4 f1 = *(const float4*)&hls[r * 136 + c + 4];
            float ss = f0.x * f0.x + f0.y * f0.y + f0.z * f0.z + f0.w * f0.w
                     + f1.x * f1.x + f1.y * f1.y + f1.z * f1.z + f1.w * f1.w;
#pragma unroll
            for (int off = 1; off < 16; off <<= 1) ss += __shfl_xor(ss, off);
            const float rs = rsqrtf(ss * (1.f / 128.f) + EPSF);
            const float4 w0 = *(const float4*)&nw2[c];
            const float4 w1 = *(const float4*)&nw2[c + 4];
            uint4 pk;
            pk.x = (uint_t)f2b(f0.x * rs * w0.x) | ((uint_t)f2b(f0.y * rs * w0.y) << 16);
            pk.y = (uint_t)f2b(f0.z * rs * w0.z) | ((uint_t)f2b(f0.w * rs * w0.w) << 16);
            pk.z = (uint_t)f2b(f1.x * rs * w1.x) | ((uint_t)f2b(f1.y * rs * w1.y) << 16);
            pk.w = (uint_t)f2b(f1.z * rs * w1.z) | ((uint_t)f2b(f1.w * rs * w1.w) << 16);
            *(uint4*)&hnb[(m0 + r) * 128 + c] = pk;
        }
    } else {
        // final rmsnorm + partial mean-pool -> part[blockIdx.x][0..127]
#pragma unroll
        for (int i = 0; i < 4; ++i) {
            const int e = i * 2048 + tid * 8;
            const int r = e >> 7, c = e & 127;
            const float4 f0 = *(const float4*)&hls[r * 136 + c];
            const float4 f1 = *(const float4*)&hls[r * 136 + c + 4];
            float ss = f0.x * f0.x + f0.y * f0.y + f0.z * f0.z + f0.w * f0.w
                     + f1.x * f1.x + f1.y * f1.y + f1.z * f1.z + f1.w * f1.w;
#pragma unroll
            for (int off = 1; off < 16; off <<= 1) ss += __shfl_xor(ss, off);
            if ((tid & 15) == 0) rstd[r] = rsqrtf(ss * (1.f / 128.f) + EPSF);
        }
        __syncthreads();
        const int d = tid & 127, hv = tid >> 7;
        float ps = 0.f;
#pragma unroll
        for (int i0 = 0; i0 < 32; ++i0) {
            const int rr = hv + 2 * i0;
            ps += hls[rr * 136 + d] * rstd[rr];
        }
        padd[tid] = ps;
        __syncthreads();
        if (tid < 128) part[blockIdx.x * 128 + tid] = (padd[tid] + padd[128 + tid]) * nw2[tid];
    }
}

// dtprep scan, wave-0-only, bit-identical to the Hillis-Steele ladder (r7)
__device__ __forceinline__ void dt_scan_wave0(
    const float* __restrict__ dtraw, const float* __restrict__ A_log,
    const float* __restrict__ dt_bias, int l, int hh, int m0, int lane,
    float* __restrict__ cumls, float* __restrict__ dtls)
{
    const float Ah = -expf(A_log[l * NH + hh]);
    const float bias = dt_bias[l * NH + hh];
    const float r0 = dtraw[(m0 + lane) * 4 + hh] + bias;
    const float r1 = dtraw[(m0 + 64 + lane) * 4 + hh] + bias;
    const float dt0 = (r0 > 20.f) ? r0 : log1pf(expf(r0));
    const float dt1 = (r1 > 20.f) ? r1 : log1pf(expf(r1));
    float v0 = dt0 * Ah, v1 = dt1 * Ah;
#pragma unroll
    for (int off = 1; off < 64; off <<= 1) {
        const int src = (lane - off) & 63;
        const float s0 = __shfl(v0, src);
        const float s1 = __shfl(v1, src);
        v0 += (lane >= off) ? s0 : 0.f;
        v1 += (lane >= off) ? s1 : s0;   // cross-half term for lane<off
    }
    v1 += v0;                             // off = 64 step
    cumls[lane] = v0; cumls[64 + lane] = v1;
    dtls[lane]  = dt0; dtls[64 + lane]  = dt1;
}

// ===== fused conv+dtprep+SSD-chunk-state (r9 proven, c==15 early exit) =====
__global__ __launch_bounds__(256) void k_ssd_state(
    const ushort_t* __restrict__ projb, const float* __restrict__ dtraw,
    const float* __restrict__ cw, const float* __restrict__ cb,
    const float* __restrict__ A_log, const float* __restrict__ dt_bias,
    float* __restrict__ zbuf, float* __restrict__ dec, int l)
{
    __shared__ ushort_t Xt[64 * 136];
    __shared__ ushort_t wB[16 * 136];
    __shared__ ushort_t pX[131 * 64];
    __shared__ ushort_t pB[131 * 16];
    __shared__ float cumls[QCH];
    __shared__ float dtls[QCH];
    const int bid = blockIdx.x;
    const int c = bid & (NC - 1);
    if (c == NC - 1) return;   // dead work: prefix uses only cc < c
    const int hh = (bid / NC) & (NH - 1);
    const int b = bid / (NC * NH);
    const int m0 = b * T_ + c * QCH;
    const int tid = threadIdx.x;
    const int lane = tid & 63;

    if (tid < 64) {
        dt_scan_wave0(dtraw, A_log, dt_bias, l, hh, m0, lane, cumls, dtls);
    } else {
        const int t0 = c * QCH;
        for (int e = tid - 64; e < 131 * 8; e += 192) {
            const int ls = e >> 3, j = e & 7;
            const int tb = t0 + ls - 3;
            uint4 v; v.x = 0u; v.y = 0u; v.z = 0u; v.w = 0u;
            if (tb >= 0) v = *(const uint4*)&projb[(b * T_ + tb) * 544 + 256 + hh * 64 + j * 8];
            *(uint4*)&pX[ls * 64 + j * 8] = v;
        }
        for (int e = tid - 64; e < 131 * 2; e += 192) {
            const int ls = e >> 1, j = e & 1;
            const int tb = t0 + ls - 3;
            uint4 v; v.x = 0u; v.y = 0u; v.z = 0u; v.w = 0u;
            if (tb >= 0) v = *(const uint4*)&projb[(b * T_ + tb) * 544 + 512 + j * 8];
            *(uint4*)&pB[ls * 16 + j * 8] = v;
        }
    }
    __syncthreads();
    const float clast = cumls[QCH - 1];

    {
        const int p = tid & 63;
        const int s0 = tid >> 6;
        const float* wp = cw + (l * CONVDIM + hh * 64 + p) * KCONV;
        const float bbv = cb[l * CONVDIM + hh * 64 + p];
#pragma unroll
        for (int pass = 0; pass < 32; ++pass) {
            const int s = pass * 4 + s0;
            float a = bbv;
#pragma unroll
            for (int k = 0; k < KCONV; ++k) a += b2f(pX[(s + k) * 64 + p]) * wp[k];
            Xt[p * 136 + s] = f2b(a / (1.f + __expf(-a)));
        }
    }
    {
        const int n = tid & 15;
        const int s0 = tid >> 4;
        const float* wp = cw + (l * CONVDIM + 256 + n) * KCONV;
        const float bbv = cb[l * CONVDIM + 256 + n];
#pragma unroll
        for (int pass = 0; pass < 8; ++pass) {
            const int s = pass * 16 + s0;
            float a = bbv;
#pragma unroll
            for (int k = 0; k < KCONV; ++k) a += b2f(pB[(s + k) * 16 + n]) * wp[k];
            const ushort_t sb = f2b(a / (1.f + __expf(-a)));
            const float w = __expf(clast - cumls[s]) * dtls[s];
            wB[n * 136 + s] = f2b(w * b2f(sb));
        }
    }
    __syncthreads();

    const int w = tid >> 6;
    const int r16 = lane & 15, q8 = (lane >> 4) * 8, q4 = (lane >> 4) * 4;
    f4v acc = (f4v)0.f;
#pragma unroll
    for (int kc = 0; kc < 128; kc += 32) {
        const bf8 a = *(const bf8*)&Xt[(w * 16 + r16) * 136 + kc + q8];
        const bf8 bb = *(const bf8*)&wB[r16 * 136 + kc + q8];
        acc = __builtin_amdgcn_mfma_f32_16x16x32_bf16(a, bb, acc, 0, 0, 0);
    }
#pragma unroll
    for (int r = 0; r < 4; ++r) {
        const int p = w * 16 + q4 + r;
        zbuf[bid * 1024 + p * 16 + r16] = acc[r];
    }
    if (tid == 0) dec[bid] = __expf(clast);
}

// ===== fused conv+dtprep+SSD-y (r7 proven) =====
__global__ __launch_bounds__(256) void k_ssd_y(
    const ushort_t* __restrict__ projb, const float* __restrict__ dtraw,
    const float* __restrict__ cw, const float* __restrict__ cb,
    const float* __restrict__ A_log, const float* __restrict__ dt_bias,
    const float* __restrict__ zbuf, const float* __restrict__ dec,
    const float* __restrict__ Dvec, ushort_t* __restrict__ yb, int l)
{
    __shared__ ushort_t Xt[64 * 136];
    __shared__ ushort_t BlsT[128 * 40];
    __shared__ ushort_t ClsT[128 * 40];
    __shared__ ushort_t Gls[128 * 136];   // staging alias: pX | pB | pC during conv
    __shared__ ushort_t Spt[64 * 40];
    __shared__ float cumls[QCH];
    __shared__ float dtls[QCH];
    ushort_t* pX = Gls;                    // 131*64 = 8384
    ushort_t* pB = Gls + 131 * 64;         // 131*16 = 2096
    ushort_t* pC = Gls + 131 * 64 + 131 * 16;
    const int bid = blockIdx.x;
    const int c = bid & (NC - 1);
    const int hh = (bid / NC) & (NH - 1);
    const int b = bid / (NC * NH);
    const int bh = bid >> 4;               // b*NH + hh (NC==16)
    const int m0 = b * T_ + c * QCH;
    const int tid = threadIdx.x;
    const int lane = tid & 63;

    if (tid < 64) {
        dt_scan_wave0(dtraw, A_log, dt_bias, l, hh, m0, lane, cumls, dtls);
    } else {
        const int t0 = c * QCH;
        for (int e = tid - 64; e < 131 * 8; e += 192) {
            const int ls = e >> 3, j = e & 7;
            const int tb = t0 + ls - 3;
            uint4 v; v.x = 0u; v.y = 0u; v.z = 0u; v.w = 0u;
            if (tb >= 0) v = *(const uint4*)&projb[(b * T_ + tb) * 544 + 256 + hh * 64 + j * 8];
            *(uint4*)&pX[ls * 64 + j * 8] = v;
        }
        for (int e = tid - 64; e < 131 * 2; e += 192) {
            const int ls = e >> 1, j = e & 1;
            const int tb = t0 + ls - 3;
            uint4 v0; v0.x = 0u; v0.y = 0u; v0.z = 0u; v0.w = 0u;
            uint4 v1 = v0;
            if (tb >= 0) {
                v0 = *(const uint4*)&projb[(b * T_ + tb) * 544 + 512 + j * 8];
                v1 = *(const uint4*)&projb[(b * T_ + tb) * 544 + 528 + j * 8];
            }
            *(uint4*)&pB[ls * 16 + j * 8] = v0;
            *(uint4*)&pC[ls * 16 + j * 8] = v1;
        }
    }
    __syncthreads();

    {
        const int p = tid & 63;
        const int s0 = tid >> 6;
        const float* wp = cw + (l * CONVDIM + hh * 64 + p) * KCONV;
        const float bbv = cb[l * CONVDIM + hh * 64 + p];
#pragma unroll
        for (int pass = 0; pass < 32; ++pass) {
            const int s = pass * 4 + s0;
            float a = bbv;
#pragma unroll
            for (int k = 0; k < KCONV; ++k) a += b2f(pX[(s + k) * 64 + p]) * wp[k];
            Xt[p * 136 + s] = f2b(a / (1.f + __expf(-a)));
        }
    }
    {
        const int n = tid & 15;
        const int s0 = tid >> 4;
        const float* wpB = cw + (l * CONVDIM + 256 + n) * KCONV;
        const float bbB = cb[l * CONVDIM + 256 + n];
        const float* wpC = cw + (l * CONVDIM + 272 + n) * KCONV;
        const float bbC = cb[l * CONVDIM + 272 + n];
#pragma unroll
        for (int pass = 0; pass < 8; ++pass) {
            const int s = pass * 16 + s0;
            float aB = bbB, aC = bbC;
#pragma unroll
            for (int k = 0; k < KCONV; ++k) {
                aB += b2f(pB[(s + k) * 16 + n]) * wpB[k];
                aC += b2f(pC[(s + k) * 16 + n]) * wpC[k];
            }
            BlsT[s * 40 + n] = f2b(aB / (1.f + __expf(-aB)));
            ClsT[s * 40 + n] = f2b(aC / (1.f + __expf(-aC)));
            BlsT[s * 40 + 16 + n] = 0;
            ClsT[s * 40 + 16 + n] = 0;
        }
    }
    {
        float4 S; S.x = 0.f; S.y = 0.f; S.z = 0.f; S.w = 0.f;
        for (int cc = 0; cc < c; ++cc) {
            const float d = dec[bh * NC + cc];
            const float4 z = *(const float4*)(zbuf + (bh * NC + cc) * 1024 + tid * 4);
            S.x = S.x * d + z.x; S.y = S.y * d + z.y;
            S.z = S.z * d + z.z; S.w = S.w * d + z.w;
        }
        const int p = tid >> 2, n = (tid & 3) * 4;
        Spt[p * 40 + n]     = f2b(S.x);
        Spt[p * 40 + n + 1] = f2b(S.y);
        Spt[p * 40 + n + 2] = f2b(S.z);
        Spt[p * 40 + n + 3] = f2b(S.w);
        Spt[p * 40 + 16 + n]     = 0;
        Spt[p * 40 + 16 + n + 1] = 0;
        Spt[p * 40 + 16 + n + 2] = 0;
        Spt[p * 40 + 16 + n + 3] = 0;
    }
    __syncthreads();   // conv + scan done; praw (Gls alias) now dead

    const int w = tid >> 6;
    const int wrow = w * 32;
    const int r16 = lane & 15, q8 = (lane >> 4) * 8, q4 = (lane >> 4) * 4;
    const float Dh = Dvec[l * NH + hh];

    bf8 cfr[2];
#pragma unroll
    for (int i = 0; i < 2; ++i)
        cfr[i] = *(const bf8*)&ClsT[(wrow + i * 16 + r16) * 40 + q8];

    float cumt[8], et[8];
#pragma unroll
    for (int i = 0; i < 2; ++i)
#pragma unroll
        for (int r = 0; r < 4; ++r) {
            const int t = wrow + i * 16 + q4 + r;
            cumt[i * 4 + r] = cumls[t];
            et[i * 4 + r] = __expf(cumls[t]);
        }

    f4v acc[2][4];
#pragma unroll
    for (int j = 0; j < 4; ++j) {
        const bf8 sf = *(const bf8*)&Spt[(j * 16 + r16) * 40 + q8];
#pragma unroll
        for (int i = 0; i < 2; ++i) {
            f4v z = (f4v)0.f;
            z = __builtin_amdgcn_mfma_f32_16x16x32_bf16(cfr[i], sf, z, 0, 0, 0);
#pragma unroll
            for (int r = 0; r < 4; ++r) {
                const int t = wrow + i * 16 + q4 + r;
                const int p = j * 16 + r16;
                acc[i][j][r] = z[r] * et[i * 4 + r] + Dh * b2f(Xt[p * 136 + t]);
            }
        }
    }

#pragma unroll
    for (int ts = 0; ts < 8; ++ts) {
        const bf8 bf = *(const bf8*)&BlsT[(ts * 16 + r16) * 40 + q8];
        const int s = ts * 16 + r16;
        const float cs = cumls[s];
        const float ds = dtls[s];
#pragma unroll
        for (int i = 0; i < 2; ++i) {
            f4v g = (f4v)0.f;
            g = __builtin_amdgcn_mfma_f32_16x16x32_bf16(cfr[i], bf, g, 0, 0, 0);
#pragma unroll
            for (int r = 0; r < 4; ++r) {
                const int t = wrow + i * 16 + q4 + r;
                const float val = (s <= t) ? __expf(cumt[i * 4 + r] - cs) * ds * g[r] : 0.f;
                Gls[t * 136 + s] = f2b(val);
            }
        }
    }
    __syncthreads();

#pragma unroll
    for (int kc = 0; kc < 128; kc += 32) {
        bf8 af[2];
#pragma unroll
        for (int i = 0; i < 2; ++i)
            af[i] = *(const bf8*)&Gls[(wrow + i * 16 + r16) * 136 + kc + q8];
#pragma unroll
        for (int j = 0; j < 4; ++j) {
            const bf8 xf = *(const bf8*)&Xt[(j * 16 + r16) * 136 + kc + q8];
#pragma unroll
            for (int i = 0; i < 2; ++i)
                acc[i][j] = __builtin_amdgcn_mfma_f32_16x16x32_bf16(af[i], xf, acc[i][j], 0, 0, 0);
        }
    }

#pragma unroll
    for (int i = 0; i < 2; ++i)
#pragma unroll
        for (int r = 0; r < 4; ++r) {
            const int t = wrow + i * 16 + q4 + r;
#pragma unroll
            for (int j = 0; j < 4; ++j) {
                const int p = j * 16 + r16;
                yb[(m0 + t) * DINNER + hh * 64 + p] = f2b(acc[i][j][r]);
            }
        }
}

// ===== pooled reduce + head GEMM (r10: 32 partial tiles per batch) =====
__global__ __launch_bounds__(256) void k_head(
    const float* __restrict__ part, const float* __restrict__ ow,
    const float* __restrict__ ob, float* __restrict__ out)
{
    __shared__ float pooled[128];
    const int b = blockIdx.x;
    const int tid = threadIdx.x;
    if (tid < 128) {
        float s = 0.f;
        for (int tile = 0; tile < 32; ++tile) s += part[(b * 32 + tile) * 128 + tid];
        pooled[tid] = s * (1.f / (float)T_);
    }
    __syncthreads();
    for (int o = tid; o < DIMX; o += 256) {
        float acc = ob[o];
#pragma unroll 4
        for (int d = 0; d < 128; ++d) acc += pooled[d] * ow[d * DIMX + o];
        out[b * DIMX + o] = acc;
    }
}

extern "C" void kernel_launch(void* const* d_in, const int* in_sizes, int n_in,
                              void* d_out, int out_size, void* d_ws, size_t ws_size,
                              hipStream_t stream)
{
    const float* x         = (const float*)d_in[0];
    const float* in_w      = (const float*)d_in[1];
    const float* in_b      = (const float*)d_in[2];
    const float* norm_w    = (const float*)d_in[3];
    const float* inproj_w  = (const float*)d_in[4];
    const float* conv_w    = (const float*)d_in[5];
    const float* conv_b    = (const float*)d_in[6];
    const float* A_log     = (const float*)d_in[7];
    const float* Dvec      = (const float*)d_in[8];
    const float* dt_bias   = (const float*)d_in[9];
    const float* gnorm_w   = (const float*)d_in[10];
    const float* outproj_w = (const float*)d_in[11];
    const float* normf_w   = (const float*)d_in[12];
    const float* out_w     = (const float*)d_in[13];
    const float* out_b     = (const float*)d_in[14];

    float* ws    = (float*)d_ws;
    float* h     = ws + OFF_H;
    float* zbuf  = ws + OFF_Z;
    float* dec   = ws + OFF_DEC;
    float* part  = ws + OFF_PART;
    float* dtraw = ws + OFF_DTRAW;
    ushort_t* hnb   = (ushort_t*)(ws + OFF_HNB);
    ushort_t* projb = (ushort_t*)(ws + OFF_PROJB);
    ushort_t* yb    = (ushort_t*)(ws + OFF_YB);
    ushort_t* wt_in  = (ushort_t*)(ws + OFF_WTIN);
    ushort_t* wt_inp = (ushort_t*)(ws + OFF_WTINP);
    ushort_t* wt_out = (ushort_t*)(ws + OFF_WTOUT);

    k_wt_all<<<68, 256, 0, stream>>>(in_w, inproj_w, outproj_w, wt_in, wt_inp, wt_out);

    // input GEMM + rmsnorm(layer 0) fused epilogue
    k_gemm_in<<<MTOK / 64, 256, 0, stream>>>(x, wt_in, in_b, norm_w, h, hnb);

    for (int l = 0; l < LLAYERS; ++l) {
        k_gemm_rms<<<dim3(MTOK / 64, 5), 256, 0, stream>>>(
            hnb, wt_inp + l * 576 * 128, projb, dtraw);
        k_ssd_state<<<B_ * NH * NC, 256, 0, stream>>>(
            projb, dtraw, conv_w, conv_b, A_log, dt_bias, zbuf, dec, l);
        k_ssd_y<<<B_ * NH * NC, 256, 0, stream>>>(
            projb, dtraw, conv_w, conv_b, A_log, dt_bias, zbuf, dec, Dvec, yb, l);
        if (l == 0) {
            k_gemm_gn<0><<<MTOK / 64, 256, 0, stream>>>(
                yb, projb, gnorm_w + l * DINNER, wt_out + l * 128 * 256, h,
                norm_w + 1 * DM, hnb, nullptr);
        } else {
            k_gemm_gn<1><<<MTOK / 64, 256, 0, stream>>>(
                yb, projb, gnorm_w + l * DINNER, wt_out + l * 128 * 256, h,
                normf_w, nullptr, part);
        }
    }

    k_head<<<B_, 256, 0, stream>>>(part, out_w, out_b, (float*)d_out);
}

// Round 11
// 246.411 us; speedup vs baseline: 1.4032x; 1.4032x over previous
//
#include <hip/hip_runtime.h>
#include <math.h>

typedef unsigned short ushort_t;
typedef unsigned int uint_t;

// Problem constants
#define B_      8
#define T_      2048
#define DIMX    512
#define DM      128
#define DINNER  256
#define NSTATE  16
#define HDIM    64
#define NH      4
#define CONVDIM 288
#define PROJ    548
#define KCONV   4
#define LLAYERS 2
#define QCH     128
#define NC      (T_/QCH)
#define EPSF    1e-5f
#define MTOK    (B_*T_)

// ---- workspace layout (float offsets) ----
#define OFF_H      0u
#define OFF_Z      20119552u
#define OFF_DEC    21168128u
#define OFF_PART   21168640u
#define OFF_WTIN   23396864u
#define OFF_WTINP  23429632u
#define OFF_WTOUT  23503360u
#define OFF_PROJB  23600000u   // ushort[MTOK*544]
#define OFF_DTRAW  28100000u   // float [MTOK*4]
#define OFF_YB     30600000u   // ushort[MTOK*256]

__device__ __forceinline__ ushort_t f2b(float f) {
    uint_t u = __builtin_bit_cast(uint_t, f);
    return (ushort_t)((u + 0x7FFFu + ((u >> 16) & 1u)) >> 16);
}
__device__ __forceinline__ float b2f(ushort_t b) {
    uint_t u = ((uint_t)b) << 16;
    return __builtin_bit_cast(float, u);
}
__device__ __forceinline__ float blo(uint_t u) { return b2f((ushort_t)(u & 0xffffu)); }
__device__ __forceinline__ float bhi(uint_t u) { return b2f((ushort_t)(u >> 16)); }

typedef short bf8 __attribute__((ext_vector_type(8)));
typedef float f4v __attribute__((ext_vector_type(4)));

// ===== all weight transposes in ONE kernel (proven r8) =====
__global__ __launch_bounds__(256) void k_wt_all(
    const float* __restrict__ in_w, const float* __restrict__ inproj_w,
    const float* __restrict__ outproj_w,
    ushort_t* __restrict__ wt_in, ushort_t* __restrict__ wt_inp,
    ushort_t* __restrict__ wt_out)
{
    __shared__ float tile[64][65];
    int idx = blockIdx.x;
    const float* W; ushort_t* Wt; int K, N, k0, n0;
    if (idx < 16) {
        W = in_w; Wt = wt_in; K = 512; N = 128;
        k0 = (idx & 7) * 64; n0 = (idx >> 3) * 64;
    } else if (idx < 52) {
        int r = idx - 16; int l = r / 18; r -= l * 18;
        W = inproj_w + l * 128 * PROJ; Wt = wt_inp + l * 576 * 128; K = 128; N = PROJ;
        k0 = (r & 1) * 64; n0 = (r >> 1) * 64;
    } else {
        int r = idx - 52; int l = r / 8; r -= l * 8;
        W = outproj_w + l * 256 * 128; Wt = wt_out + l * 128 * 256; K = 256; N = 128;
        k0 = (r & 3) * 64; n0 = (r >> 2) * 64;
    }
    const int tid = threadIdx.x;
#pragma unroll
    for (int it = 0; it < 16; ++it) {
        const int e = it * 256 + tid;
        const int kk = e >> 6, nn = e & 63;
        tile[kk][nn] = (n0 + nn < N) ? W[(k0 + kk) * N + (n0 + nn)] : 0.f;
    }
    __syncthreads();
#pragma unroll
    for (int it = 0; it < 16; ++it) {
        const int e = it * 256 + tid;
        const int nn = e >> 6, kk = e & 63;
        Wt[(n0 + nn) * K + k0 + kk] = f2b(tile[kk][nn]);
    }
}

// ===== input GEMM, n-tile PAIRED (r9): A (fp32 x -> bf16 pack) staged ONCE
// per kc-chunk, both 64-col n-tiles consumed before restaging. =====
__global__ __launch_bounds__(256) void k_gemm_in(
    const float* __restrict__ x, const ushort_t* __restrict__ Bt,
    const float* __restrict__ ib, float* __restrict__ C)
{
    __shared__ ushort_t Als[64 * 136];
    __shared__ ushort_t Bls[64 * 136];
    const int m0 = blockIdx.x * 64;
    const int tid = threadIdx.x;
    const int lane = tid & 63, w = tid >> 6;
    const int wm = (w >> 1) * 32, wn = (w & 1) * 32;
    const int r16 = lane & 15, q8 = (lane >> 4) * 8;

    f4v acc[2][2][2];   // [half][i][j]
#pragma unroll
    for (int hf = 0; hf < 2; ++hf)
#pragma unroll
        for (int i = 0; i < 2; ++i)
#pragma unroll
            for (int j = 0; j < 2; ++j) acc[hf][i][j] = (f4v)0.f;

    for (int kc = 0; kc < 512; kc += 128) {
        // A staging + fp32->bf16 pack: once per kc
#pragma unroll
        for (int i = 0; i < 4; ++i) {
            const int e = i * 2048 + tid * 8;
            const int r = e >> 7, c = e & 127;
            const float4 f0 = *(const float4*)&x[(m0 + r) * 512 + kc + c];
            const float4 f1 = *(const float4*)&x[(m0 + r) * 512 + kc + c + 4];
            uint4 pk;
            pk.x = (uint_t)f2b(f0.x) | ((uint_t)f2b(f0.y) << 16);
            pk.y = (uint_t)f2b(f0.z) | ((uint_t)f2b(f0.w) << 16);
            pk.z = (uint_t)f2b(f1.x) | ((uint_t)f2b(f1.y) << 16);
            pk.w = (uint_t)f2b(f1.z) | ((uint_t)f2b(f1.w) << 16);
            *(uint4*)&Als[r * 136 + c] = pk;
        }
#pragma unroll
        for (int hf = 0; hf < 2; ++hf) {
            const int n0 = hf * 64;
#pragma unroll
            for (int i = 0; i < 4; ++i) {
                const int e = i * 2048 + tid * 8;
                const int r = e >> 7, c = e & 127;
                *(uint4*)&Bls[r * 136 + c] = *(const uint4*)&Bt[(n0 + r) * 512 + kc + c];
            }
            __syncthreads();
#pragma unroll
            for (int kk = 0; kk < 128; kk += 32) {
                const bf8 a0 = *(const bf8*)&Als[(wm + r16) * 136 + kk + q8];
                const bf8 a1 = *(const bf8*)&Als[(wm + 16 + r16) * 136 + kk + q8];
                const bf8 b0 = *(const bf8*)&Bls[(wn + r16) * 136 + kk + q8];
                const bf8 b1 = *(const bf8*)&Bls[(wn + 16 + r16) * 136 + kk + q8];
                acc[hf][0][0] = __builtin_amdgcn_mfma_f32_16x16x32_bf16(a0, b0, acc[hf][0][0], 0, 0, 0);
                acc[hf][0][1] = __builtin_amdgcn_mfma_f32_16x16x32_bf16(a0, b1, acc[hf][0][1], 0, 0, 0);
                acc[hf][1][0] = __builtin_amdgcn_mfma_f32_16x16x32_bf16(a1, b0, acc[hf][1][0], 0, 0, 0);
                acc[hf][1][1] = __builtin_amdgcn_mfma_f32_16x16x32_bf16(a1, b1, acc[hf][1][1], 0, 0, 0);
            }
            __syncthreads();
        }
    }
    const int q4 = (lane >> 4) * 4;
#pragma unroll
    for (int hf = 0; hf < 2; ++hf)
#pragma unroll
        for (int i = 0; i < 2; ++i)
#pragma unroll
            for (int j = 0; j < 2; ++j)
#pragma unroll
                for (int r = 0; r < 4; ++r) {
                    const int grow = m0 + wm + i * 16 + q4 + r;
                    const int gcol = hf * 64 + wn + j * 16 + r16;
                    C[grow * 128 + gcol] = acc[hf][i][j][r] + ib[gcol];
                }
}

// ===== inproj GEMM + inline RMSNorm — n-tile pairing (r8 proven) =====
__global__ __launch_bounds__(256) void k_gemm_rms(
    const float* __restrict__ h, const float* __restrict__ nw,
    const ushort_t* __restrict__ Bt, ushort_t* __restrict__ projb,
    float* __restrict__ dtraw)
{
    __shared__ ushort_t Als[64 * 136];
    __shared__ ushort_t Bls[64 * 136];
    const int m0 = blockIdx.x * 64;
    const int tid = threadIdx.x;
    const int lane = tid & 63, w = tid >> 6;
    const int wm = (w >> 1) * 32, wn = (w & 1) * 32;
    const int r16 = lane & 15, q8 = (lane >> 4) * 8;
    const int q4 = (lane >> 4) * 4;

    // A staging + inline rmsnorm: ONCE per block
#pragma unroll
    for (int i = 0; i < 4; ++i) {
        const int e = i * 2048 + tid * 8;
        const int r = e >> 7, c = e & 127;
        const float4 f0 = *(const float4*)&h[(m0 + r) * 128 + c];
        const float4 f1 = *(const float4*)&h[(m0 + r) * 128 + c + 4];
        float ss = f0.x * f0.x + f0.y * f0.y + f0.z * f0.z + f0.w * f0.w
                 + f1.x * f1.x + f1.y * f1.y + f1.z * f1.z + f1.w * f1.w;
#pragma unroll
        for (int off = 1; off < 16; off <<= 1) ss += __shfl_xor(ss, off);
        const float rs = rsqrtf(ss * (1.f / 128.f) + EPSF);
        const float4 w0 = *(const float4*)&nw[c];
        const float4 w1 = *(const float4*)&nw[c + 4];
        uint4 pk;
        pk.x = (uint_t)f2b(f0.x * rs * w0.x) | ((uint_t)f2b(f0.y * rs * w0.y) << 16);
        pk.y = (uint_t)f2b(f0.z * rs * w0.z) | ((uint_t)f2b(f0.w * rs * w0.w) << 16);
        pk.z = (uint_t)f2b(f1.x * rs * w1.x) | ((uint_t)f2b(f1.y * rs * w1.y) << 16);
        pk.w = (uint_t)f2b(f1.z * rs * w1.z) | ((uint_t)f2b(f1.w * rs * w1.w) << 16);
        *(uint4*)&Als[r * 136 + c] = pk;
    }

#pragma unroll
    for (int half = 0; half < 2; ++half) {
        const int n0 = blockIdx.y * 128 + half * 64;
        if (n0 >= 576) break;   // phantom tile at pair 4
#pragma unroll
        for (int i = 0; i < 4; ++i) {
            const int e = i * 2048 + tid * 8;
            const int r = e >> 7, c = e & 127;
            *(uint4*)&Bls[r * 136 + c] = *(const uint4*)&Bt[(n0 + r) * 128 + c];
        }
        __syncthreads();

        f4v acc[2][2];
#pragma unroll
        for (int i = 0; i < 2; ++i)
#pragma unroll
            for (int j = 0; j < 2; ++j) acc[i][j] = (f4v)0.f;
#pragma unroll
        for (int kk = 0; kk < 128; kk += 32) {
            const bf8 a0 = *(const bf8*)&Als[(wm + r16) * 136 + kk + q8];
            const bf8 a1 = *(const bf8*)&Als[(wm + 16 + r16) * 136 + kk + q8];
            const bf8 b0 = *(const bf8*)&Bls[(wn + r16) * 136 + kk + q8];
            const bf8 b1 = *(const bf8*)&Bls[(wn + 16 + r16) * 136 + kk + q8];
            acc[0][0] = __builtin_amdgcn_mfma_f32_16x16x32_bf16(a0, b0, acc[0][0], 0, 0, 0);
            acc[0][1] = __builtin_amdgcn_mfma_f32_16x16x32_bf16(a0, b1, acc[0][1], 0, 0, 0);
            acc[1][0] = __builtin_amdgcn_mfma_f32_16x16x32_bf16(a1, b0, acc[1][0], 0, 0, 0);
            acc[1][1] = __builtin_amdgcn_mfma_f32_16x16x32_bf16(a1, b1, acc[1][1], 0, 0, 0);
        }
        __syncthreads();   // protect Bls before restage (half 1)

#pragma unroll
        for (int i = 0; i < 2; ++i)
#pragma unroll
            for (int j = 0; j < 2; ++j)
#pragma unroll
                for (int r = 0; r < 4; ++r) {
                    const int grow = m0 + wm + i * 16 + q4 + r;
                    const int gcol = n0 + wn + j * 16 + r16;
                    if (gcol < 544) projb[grow * 544 + gcol] = f2b(acc[i][j][r]);
                    else if (gcol < PROJ) dtraw[grow * 4 + (gcol - 544)] = acc[i][j][r];
                }
    }
}

// ===== outproj GEMM + inline gated-RMSNorm — n-tile PAIRED (r9) =====
__global__ __launch_bounds__(256) void k_gemm_gn(
    const ushort_t* __restrict__ yb, const ushort_t* __restrict__ projb,
    const float* __restrict__ gw, const ushort_t* __restrict__ Bt,
    float* __restrict__ C)
{
    __shared__ ushort_t Als[64 * 264];
    __shared__ ushort_t Bls[64 * 136];
    const int m0 = blockIdx.x * 64;
    const int tid = threadIdx.x;
    const int lane = tid & 63, w = tid >> 6;
    const int wm = (w >> 1) * 32, wn = (w & 1) * 32;
    const int r16 = lane & 15, q8 = (lane >> 4) * 8;
    const int q4 = (lane >> 4) * 4;

#pragma unroll
    for (int i = 0; i < 8; ++i) {
        const int e = i * 2048 + tid * 8;
        const int r = e >> 8, c = e & 255;
        const uint4 yv = *(const uint4*)&yb[(m0 + r) * 256 + c];
        const uint4 gv = *(const uint4*)&projb[(m0 + r) * 544 + c];
        const float g0 = blo(gv.x), g1 = bhi(gv.x), g2 = blo(gv.y), g3 = bhi(gv.y);
        const float g4 = blo(gv.z), g5 = bhi(gv.z), g6 = blo(gv.w), g7 = bhi(gv.w);
        float v0 = blo(yv.x) * (g0 / (1.f + __expf(-g0)));
        float v1 = bhi(yv.x) * (g1 / (1.f + __expf(-g1)));
        float v2 = blo(yv.y) * (g2 / (1.f + __expf(-g2)));
        float v3 = bhi(yv.y) * (g3 / (1.f + __expf(-g3)));
        float v4 = blo(yv.z) * (g4 / (1.f + __expf(-g4)));
        float v5 = bhi(yv.z) * (g5 / (1.f + __expf(-g5)));
        float v6 = blo(yv.w) * (g6 / (1.f + __expf(-g6)));
        float v7 = bhi(yv.w) * (g7 / (1.f + __expf(-g7)));
        float ss = v0 * v0 + v1 * v1 + v2 * v2 + v3 * v3
                 + v4 * v4 + v5 * v5 + v6 * v6 + v7 * v7;
#pragma unroll
        for (int off = 1; off < 32; off <<= 1) ss += __shfl_xor(ss, off);
        const float rs = rsqrtf(ss * (1.f / 256.f) + EPSF);
        const float4 w0 = *(const float4*)&gw[c];
        const float4 w1 = *(const float4*)&gw[c + 4];
        uint4 pk;
        pk.x = (uint_t)f2b(v0 * rs * w0.x) | ((uint_t)f2b(v1 * rs * w0.y) << 16);
        pk.y = (uint_t)f2b(v2 * rs * w0.z) | ((uint_t)f2b(v3 * rs * w0.w) << 16);
        pk.z = (uint_t)f2b(v4 * rs * w1.x) | ((uint_t)f2b(v5 * rs * w1.y) << 16);
        pk.w = (uint_t)f2b(v6 * rs * w1.z) | ((uint_t)f2b(v7 * rs * w1.w) << 16);
        *(uint4*)&Als[r * 264 + c] = pk;
    }

#pragma unroll
    for (int half = 0; half < 2; ++half) {
        const int n0 = half * 64;
        f4v acc[2][2];
#pragma unroll
        for (int i = 0; i < 2; ++i)
#pragma unroll
            for (int j = 0; j < 2; ++j) acc[i][j] = (f4v)0.f;

        for (int kc = 0; kc < 256; kc += 128) {
#pragma unroll
            for (int i = 0; i < 4; ++i) {
                const int e = i * 2048 + tid * 8;
                const int r = e >> 7, c = e & 127;
                *(uint4*)&Bls[r * 136 + c] = *(const uint4*)&Bt[(n0 + r) * 256 + kc + c];
            }
            __syncthreads();
#pragma unroll
            for (int kk = 0; kk < 128; kk += 32) {
                const bf8 a0 = *(const bf8*)&Als[(wm + r16) * 264 + kc + kk + q8];
                const bf8 a1 = *(const bf8*)&Als[(wm + 16 + r16) * 264 + kc + kk + q8];
                const bf8 b0 = *(const bf8*)&Bls[(wn + r16) * 136 + kk + q8];
                const bf8 b1 = *(const bf8*)&Bls[(wn + 16 + r16) * 136 + kk + q8];
                acc[0][0] = __builtin_amdgcn_mfma_f32_16x16x32_bf16(a0, b0, acc[0][0], 0, 0, 0);
                acc[0][1] = __builtin_amdgcn_mfma_f32_16x16x32_bf16(a0, b1, acc[0][1], 0, 0, 0);
                acc[1][0] = __builtin_amdgcn_mfma_f32_16x16x32_bf16(a1, b0, acc[1][0], 0, 0, 0);
                acc[1][1] = __builtin_amdgcn_mfma_f32_16x16x32_bf16(a1, b1, acc[1][1], 0, 0, 0);
            }
            __syncthreads();
        }

#pragma unroll
        for (int i = 0; i < 2; ++i)
#pragma unroll
            for (int j = 0; j < 2; ++j)
#pragma unroll
                for (int r = 0; r < 4; ++r) {
                    const int grow = m0 + wm + i * 16 + q4 + r;
                    const int gcol = n0 + wn + j * 16 + r16;
                    C[grow * 128 + gcol] += acc[i][j][r];
                }
    }
}

// dtprep scan, wave-0-only, bit-identical to the Hillis-Steele ladder (r7)
__device__ __forceinline__ void dt_scan_wave0(
    const float* __restrict__ dtraw, const float* __restrict__ A_log,
    const float* __restrict__ dt_bias, int l, int hh, int m0, int lane,
    float* __restrict__ cumls, float* __restrict__ dtls)
{
    const float Ah = -expf(A_log[l * NH + hh]);
    const float bias = dt_bias[l * NH + hh];
    const float r0 = dtraw[(m0 + lane) * 4 + hh] + bias;
    const float r1 = dtraw[(m0 + 64 + lane) * 4 + hh] + bias;
    const float dt0 = (r0 > 20.f) ? r0 : log1pf(expf(r0));
    const float dt1 = (r1 > 20.f) ? r1 : log1pf(expf(r1));
    float v0 = dt0 * Ah, v1 = dt1 * Ah;
#pragma unroll
    for (int off = 1; off < 64; off <<= 1) {
        const int src = (lane - off) & 63;
        const float s0 = __shfl(v0, src);
        const float s1 = __shfl(v1, src);
        v0 += (lane >= off) ? s0 : 0.f;
        v1 += (lane >= off) ? s1 : s0;   // cross-half term for lane<off
    }
    v1 += v0;                             // off = 64 step
    cumls[lane] = v0; cumls[64 + lane] = v1;
    dtls[lane]  = dt0; dtls[64 + lane]  = dt1;
}

// ===== fused conv+dtprep+SSD-chunk-state (r9 proven, c==15 early exit) =====
__global__ __launch_bounds__(256) void k_ssd_state(
    const ushort_t* __restrict__ projb, const float* __restrict__ dtraw,
    const float* __restrict__ cw, const float* __restrict__ cb,
    const float* __restrict__ A_log, const float* __restrict__ dt_bias,
    float* __restrict__ zbuf, float* __restrict__ dec, int l)
{
    __shared__ ushort_t Xt[64 * 136];
    __shared__ ushort_t wB[16 * 136];
    __shared__ ushort_t pX[131 * 64];
    __shared__ ushort_t pB[131 * 16];
    __shared__ float cumls[QCH];
    __shared__ float dtls[QCH];
    const int bid = blockIdx.x;
    const int c = bid & (NC - 1);
    if (c == NC - 1) return;   // dead work: prefix uses only cc < c
    const int hh = (bid / NC) & (NH - 1);
    const int b = bid / (NC * NH);
    const int m0 = b * T_ + c * QCH;
    const int tid = threadIdx.x;
    const int lane = tid & 63;

    if (tid < 64) {
        dt_scan_wave0(dtraw, A_log, dt_bias, l, hh, m0, lane, cumls, dtls);
    } else {
        const int t0 = c * QCH;
        for (int e = tid - 64; e < 131 * 8; e += 192) {
            const int ls = e >> 3, j = e & 7;
            const int tb = t0 + ls - 3;
            uint4 v; v.x = 0u; v.y = 0u; v.z = 0u; v.w = 0u;
            if (tb >= 0) v = *(const uint4*)&projb[(b * T_ + tb) * 544 + 256 + hh * 64 + j * 8];
            *(uint4*)&pX[ls * 64 + j * 8] = v;
        }
        for (int e = tid - 64; e < 131 * 2; e += 192) {
            const int ls = e >> 1, j = e & 1;
            const int tb = t0 + ls - 3;
            uint4 v; v.x = 0u; v.y = 0u; v.z = 0u; v.w = 0u;
            if (tb >= 0) v = *(const uint4*)&projb[(b * T_ + tb) * 544 + 512 + j * 8];
            *(uint4*)&pB[ls * 16 + j * 8] = v;
        }
    }
    __syncthreads();
    const float clast = cumls[QCH - 1];

    {
        const int p = tid & 63;
        const int s0 = tid >> 6;
        const float* wp = cw + (l * CONVDIM + hh * 64 + p) * KCONV;
        const float bbv = cb[l * CONVDIM + hh * 64 + p];
#pragma unroll
        for (int pass = 0; pass < 32; ++pass) {
            const int s = pass * 4 + s0;
            float a = bbv;
#pragma unroll
            for (int k = 0; k < KCONV; ++k) a += b2f(pX[(s + k) * 64 + p]) * wp[k];
            Xt[p * 136 + s] = f2b(a / (1.f + __expf(-a)));
        }
    }
    {
        const int n = tid & 15;
        const int s0 = tid >> 4;
        const float* wp = cw + (l * CONVDIM + 256 + n) * KCONV;
        const float bbv = cb[l * CONVDIM + 256 + n];
#pragma unroll
        for (int pass = 0; pass < 8; ++pass) {
            const int s = pass * 16 + s0;
            float a = bbv;
#pragma unroll
            for (int k = 0; k < KCONV; ++k) a += b2f(pB[(s + k) * 16 + n]) * wp[k];
            const ushort_t sb = f2b(a / (1.f + __expf(-a)));
            const float w = __expf(clast - cumls[s]) * dtls[s];
            wB[n * 136 + s] = f2b(w * b2f(sb));
        }
    }
    __syncthreads();

    const int w = tid >> 6;
    const int r16 = lane & 15, q8 = (lane >> 4) * 8, q4 = (lane >> 4) * 4;
    f4v acc = (f4v)0.f;
#pragma unroll
    for (int kc = 0; kc < 128; kc += 32) {
        const bf8 a = *(const bf8*)&Xt[(w * 16 + r16) * 136 + kc + q8];
        const bf8 bb = *(const bf8*)&wB[r16 * 136 + kc + q8];
        acc = __builtin_amdgcn_mfma_f32_16x16x32_bf16(a, bb, acc, 0, 0, 0);
    }
#pragma unroll
    for (int r = 0; r < 4; ++r) {
        const int p = w * 16 + q4 + r;
        zbuf[bid * 1024 + p * 16 + r16] = acc[r];
    }
    if (tid == 0) dec[bid] = __expf(clast);
}

// ===== fused conv+dtprep+SSD-y (r7 proven) =====
__global__ __launch_bounds__(256) void k_ssd_y(
    const ushort_t* __restrict__ projb, const float* __restrict__ dtraw,
    const float* __restrict__ cw, const float* __restrict__ cb,
    const float* __restrict__ A_log, const float* __restrict__ dt_bias,
    const float* __restrict__ zbuf, const float* __restrict__ dec,
    const float* __restrict__ Dvec, ushort_t* __restrict__ yb, int l)
{
    __shared__ ushort_t Xt[64 * 136];
    __shared__ ushort_t BlsT[128 * 40];
    __shared__ ushort_t ClsT[128 * 40];
    __shared__ ushort_t Gls[128 * 136];   // staging alias: pX | pB | pC during conv
    __shared__ ushort_t Spt[64 * 40];
    __shared__ float cumls[QCH];
    __shared__ float dtls[QCH];
    ushort_t* pX = Gls;                    // 131*64 = 8384
    ushort_t* pB = Gls + 131 * 64;         // 131*16 = 2096
    ushort_t* pC = Gls + 131 * 64 + 131 * 16;
    const int bid = blockIdx.x;
    const int c = bid & (NC - 1);
    const int hh = (bid / NC) & (NH - 1);
    const int b = bid / (NC * NH);
    const int bh = bid >> 4;               // b*NH + hh (NC==16)
    const int m0 = b * T_ + c * QCH;
    const int tid = threadIdx.x;
    const int lane = tid & 63;

    if (tid < 64) {
        dt_scan_wave0(dtraw, A_log, dt_bias, l, hh, m0, lane, cumls, dtls);
    } else {
        const int t0 = c * QCH;
        for (int e = tid - 64; e < 131 * 8; e += 192) {
            const int ls = e >> 3, j = e & 7;
            const int tb = t0 + ls - 3;
            uint4 v; v.x = 0u; v.y = 0u; v.z = 0u; v.w = 0u;
            if (tb >= 0) v = *(const uint4*)&projb[(b * T_ + tb) * 544 + 256 + hh * 64 + j * 8];
            *(uint4*)&pX[ls * 64 + j * 8] = v;
        }
        for (int e = tid - 64; e < 131 * 2; e += 192) {
            const int ls = e >> 1, j = e & 1;
            const int tb = t0 + ls - 3;
            uint4 v0; v0.x = 0u; v0.y = 0u; v0.z = 0u; v0.w = 0u;
            uint4 v1 = v0;
            if (tb >= 0) {
                v0 = *(const uint4*)&projb[(b * T_ + tb) * 544 + 512 + j * 8];
                v1 = *(const uint4*)&projb[(b * T_ + tb) * 544 + 528 + j * 8];
            }
            *(uint4*)&pB[ls * 16 + j * 8] = v0;
            *(uint4*)&pC[ls * 16 + j * 8] = v1;
        }
    }
    __syncthreads();

    {
        const int p = tid & 63;
        const int s0 = tid >> 6;
        const float* wp = cw + (l * CONVDIM + hh * 64 + p) * KCONV;
        const float bbv = cb[l * CONVDIM + hh * 64 + p];
#pragma unroll
        for (int pass = 0; pass < 32; ++pass) {
            const int s = pass * 4 + s0;
            float a = bbv;
#pragma unroll
            for (int k = 0; k < KCONV; ++k) a += b2f(pX[(s + k) * 64 + p]) * wp[k];
            Xt[p * 136 + s] = f2b(a / (1.f + __expf(-a)));
        }
    }
    {
        const int n = tid & 15;
        const int s0 = tid >> 4;
        const float* wpB = cw + (l * CONVDIM + 256 + n) * KCONV;
        const float bbB = cb[l * CONVDIM + 256 + n];
        const float* wpC = cw + (l * CONVDIM + 272 + n) * KCONV;
        const float bbC = cb[l * CONVDIM + 272 + n];
#pragma unroll
        for (int pass = 0; pass < 8; ++pass) {
            const int s = pass * 16 + s0;
            float aB = bbB, aC = bbC;
#pragma unroll
            for (int k = 0; k < KCONV; ++k) {
                aB += b2f(pB[(s + k) * 16 + n]) * wpB[k];
                aC += b2f(pC[(s + k) * 16 + n]) * wpC[k];
            }
            BlsT[s * 40 + n] = f2b(aB / (1.f + __expf(-aB)));
            ClsT[s * 40 + n] = f2b(aC / (1.f + __expf(-aC)));
            BlsT[s * 40 + 16 + n] = 0;
            ClsT[s * 40 + 16 + n] = 0;
        }
    }
    {
        float4 S; S.x = 0.f; S.y = 0.f; S.z = 0.f; S.w = 0.f;
        for (int cc = 0; cc < c; ++cc) {
            const float d = dec[bh * NC + cc];
            const float4 z = *(const float4*)(zbuf + (bh * NC + cc) * 1024 + tid * 4);
            S.x = S.x * d + z.x; S.y = S.y * d + z.y;
            S.z = S.z * d + z.z; S.w = S.w * d + z.w;
        }
        const int p = tid >> 2, n = (tid & 3) * 4;
        Spt[p * 40 + n]     = f2b(S.x);
        Spt[p * 40 + n + 1] = f2b(S.y);
        Spt[p * 40 + n + 2] = f2b(S.z);
        Spt[p * 40 + n + 3] = f2b(S.w);
        Spt[p * 40 + 16 + n]     = 0;
        Spt[p * 40 + 16 + n + 1] = 0;
        Spt[p * 40 + 16 + n + 2] = 0;
        Spt[p * 40 + 16 + n + 3] = 0;
    }
    __syncthreads();   // conv + scan done; praw (Gls alias) now dead

    const int w = tid >> 6;
    const int wrow = w * 32;
    const int r16 = lane & 15, q8 = (lane >> 4) * 8, q4 = (lane >> 4) * 4;
    const float Dh = Dvec[l * NH + hh];

    bf8 cfr[2];
#pragma unroll
    for (int i = 0; i < 2; ++i)
        cfr[i] = *(const bf8*)&ClsT[(wrow + i * 16 + r16) * 40 + q8];

    float cumt[8], et[8];
#pragma unroll
    for (int i = 0; i < 2; ++i)
#pragma unroll
        for (int r = 0; r < 4; ++r) {
            const int t = wrow + i * 16 + q4 + r;
            cumt[i * 4 + r] = cumls[t];
            et[i * 4 + r] = __expf(cumls[t]);
        }

    f4v acc[2][4];
#pragma unroll
    for (int j = 0; j < 4; ++j) {
        const bf8 sf = *(const bf8*)&Spt[(j * 16 + r16) * 40 + q8];
#pragma unroll
        for (int i = 0; i < 2; ++i) {
            f4v z = (f4v)0.f;
            z = __builtin_amdgcn_mfma_f32_16x16x32_bf16(cfr[i], sf, z, 0, 0, 0);
#pragma unroll
            for (int r = 0; r < 4; ++r) {
                const int t = wrow + i * 16 + q4 + r;
                const int p = j * 16 + r16;
                acc[i][j][r] = z[r] * et[i * 4 + r] + Dh * b2f(Xt[p * 136 + t]);
            }
        }
    }

#pragma unroll
    for (int ts = 0; ts < 8; ++ts) {
        const bf8 bf = *(const bf8*)&BlsT[(ts * 16 + r16) * 40 + q8];
        const int s = ts * 16 + r16;
        const float cs = cumls[s];
        const float ds = dtls[s];
#pragma unroll
        for (int i = 0; i < 2; ++i) {
            f4v g = (f4v)0.f;
            g = __builtin_amdgcn_mfma_f32_16x16x32_bf16(cfr[i], bf, g, 0, 0, 0);
#pragma unroll
            for (int r = 0; r < 4; ++r) {
                const int t = wrow + i * 16 + q4 + r;
                const float val = (s <= t) ? __expf(cumt[i * 4 + r] - cs) * ds * g[r] : 0.f;
                Gls[t * 136 + s] = f2b(val);
            }
        }
    }
    __syncthreads();

#pragma unroll
    for (int kc = 0; kc < 128; kc += 32) {
        bf8 af[2];
#pragma unroll
        for (int i = 0; i < 2; ++i)
            af[i] = *(const bf8*)&Gls[(wrow + i * 16 + r16) * 136 + kc + q8];
#pragma unroll
        for (int j = 0; j < 4; ++j) {
            const bf8 xf = *(const bf8*)&Xt[(j * 16 + r16) * 136 + kc + q8];
#pragma unroll
            for (int i = 0; i < 2; ++i)
                acc[i][j] = __builtin_amdgcn_mfma_f32_16x16x32_bf16(af[i], xf, acc[i][j], 0, 0, 0);
        }
    }

#pragma unroll
    for (int i = 0; i < 2; ++i)
#pragma unroll
        for (int r = 0; r < 4; ++r) {
            const int t = wrow + i * 16 + q4 + r;
#pragma unroll
            for (int j = 0; j < 4; ++j) {
                const int p = j * 16 + r16;
                yb[(m0 + t) * DINNER + hh * 64 + p] = f2b(acc[i][j][r]);
            }
        }
}

// ===== final rmsnorm + partial mean-pool (proven) =====
__global__ __launch_bounds__(256) void k_finalnorm_pool(
    const float* __restrict__ h, const float* __restrict__ nfw,
    float* __restrict__ part)
{
    __shared__ float ht[2048];
    __shared__ float red[256];
    __shared__ float rstd[16];
    __shared__ float padd[256];
    const int tile = blockIdx.x & 127;
    const int b = blockIdx.x >> 7;
    const int m0 = b * T_ + tile * 16;
    const int tid = threadIdx.x;
    for (int e = tid; e < 2048; e += 256) ht[e] = h[m0 * DM + e];
    __syncthreads();
    {
        const int tg = tid >> 4, j0 = tid & 15;
        float p = 0.f;
#pragma unroll
        for (int k = 0; k < 8; ++k) { const float v = ht[tg * 128 + j0 + 16 * k]; p += v * v; }
        red[tid] = p;
    }
    __syncthreads();
    if (tid < 16) {
        float s = 0.f;
#pragma unroll
        for (int q = 0; q < 16; ++q) s += red[tid * 16 + q];
        rstd[tid] = rsqrtf(s * (1.f / 128.f) + EPSF);
    }
    __syncthreads();
    const int d = tid & 127, half = tid >> 7;
    float ps = 0.f;
#pragma unroll
    for (int i0 = 0; i0 < 8; ++i0) { const int i = half + 2 * i0; ps += ht[i * 128 + d] * rstd[i]; }
    padd[tid] = ps;
    __syncthreads();
    if (tid < 128) part[(b * 128 + tile) * 128 + tid] = (padd[tid] + padd[128 + tid]) * nfw[tid];
}

// ===== pooled reduce + head GEMM (proven) =====
__global__ __launch_bounds__(256) void k_head(
    const float* __restrict__ part, const float* __restrict__ ow,
    const float* __restrict__ ob, float* __restrict__ out)
{
    __shared__ float pooled[128];
    const int b = blockIdx.x;
    const int tid = threadIdx.x;
    if (tid < 128) {
        float s = 0.f;
        for (int tile = 0; tile < 128; ++tile) s += part[(b * 128 + tile) * 128 + tid];
        pooled[tid] = s * (1.f / (float)T_);
    }
    __syncthreads();
    for (int o = tid; o < DIMX; o += 256) {
        float acc = ob[o];
#pragma unroll 4
        for (int d = 0; d < 128; ++d) acc += pooled[d] * ow[d * DIMX + o];
        out[b * DIMX + o] = acc;
    }
}

extern "C" void kernel_launch(void* const* d_in, const int* in_sizes, int n_in,
                              void* d_out, int out_size, void* d_ws, size_t ws_size,
                              hipStream_t stream)
{
    const float* x         = (const float*)d_in[0];
    const float* in_w      = (const float*)d_in[1];
    const float* in_b      = (const float*)d_in[2];
    const float* norm_w    = (const float*)d_in[3];
    const float* inproj_w  = (const float*)d_in[4];
    const float* conv_w    = (const float*)d_in[5];
    const float* conv_b    = (const float*)d_in[6];
    const float* A_log     = (const float*)d_in[7];
    const float* Dvec      = (const float*)d_in[8];
    const float* dt_bias   = (const float*)d_in[9];
    const float* gnorm_w   = (const float*)d_in[10];
    const float* outproj_w = (const float*)d_in[11];
    const float* normf_w   = (const float*)d_in[12];
    const float* out_w     = (const float*)d_in[13];
    const float* out_b     = (const float*)d_in[14];

    float* ws    = (float*)d_ws;
    float* h     = ws + OFF_H;
    float* zbuf  = ws + OFF_Z;
    float* dec   = ws + OFF_DEC;
    float* part  = ws + OFF_PART;
    float* dtraw = ws + OFF_DTRAW;
    ushort_t* projb = (ushort_t*)(ws + OFF_PROJB);
    ushort_t* yb    = (ushort_t*)(ws + OFF_YB);
    ushort_t* wt_in  = (ushort_t*)(ws + OFF_WTIN);
    ushort_t* wt_inp = (ushort_t*)(ws + OFF_WTINP);
    ushort_t* wt_out = (ushort_t*)(ws + OFF_WTOUT);

    k_wt_all<<<68, 256, 0, stream>>>(in_w, inproj_w, outproj_w, wt_in, wt_inp, wt_out);

    k_gemm_in<<<MTOK / 64, 256, 0, stream>>>(x, wt_in, in_b, h);

    for (int l = 0; l < LLAYERS; ++l) {
        k_gemm_rms<<<dim3(MTOK / 64, 5), 256, 0, stream>>>(
            h, norm_w + l * DM, wt_inp + l * 576 * 128, projb, dtraw);
        k_ssd_state<<<B_ * NH * NC, 256, 0, stream>>>(
            projb, dtraw, conv_w, conv_b, A_log, dt_bias, zbuf, dec, l);
        k_ssd_y<<<B_ * NH * NC, 256, 0, stream>>>(
            projb, dtraw, conv_w, conv_b, A_log, dt_bias, zbuf, dec, Dvec, yb, l);
        k_gemm_gn<<<MTOK / 64, 256, 0, stream>>>(
            yb, projb, gnorm_w + l * DINNER, wt_out + l * 128 * 256, h);
    }

    k_finalnorm_pool<<<B_ * (T_ / 16), 256, 0, stream>>>(h, normf_w, part);
    k_head<<<B_, 256, 0, stream>>>(part, out_w, out_b, (float*)d_out);
}

// Round 12
// 240.888 us; speedup vs baseline: 1.4353x; 1.0229x over previous
//
#include <hip/hip_runtime.h>
#include <math.h>

typedef unsigned short ushort_t;
typedef unsigned int uint_t;

// Problem constants
#define B_      8
#define T_      2048
#define DIMX    512
#define DM      128
#define DINNER  256
#define NSTATE  16
#define HDIM    64
#define NH      4
#define CONVDIM 288
#define PROJ    548
#define KCONV   4
#define LLAYERS 2
#define QCH     128
#define NC      (T_/QCH)
#define EPSF    1e-5f
#define MTOK    (B_*T_)

// ---- workspace layout (float offsets) ----
#define OFF_H      0u
#define OFF_Z      20119552u
#define OFF_DEC    21168128u
#define OFF_PART   21168640u
#define OFF_WTIN   23396864u
#define OFF_WTINP  23429632u
#define OFF_WTOUT  23503360u
#define OFF_PROJB  23600000u   // ushort[MTOK*544]
#define OFF_DTRAW  28100000u   // float [MTOK*4]
#define OFF_YB     30600000u   // ushort[MTOK*256]

__device__ __forceinline__ ushort_t f2b(float f) {
    uint_t u = __builtin_bit_cast(uint_t, f);
    return (ushort_t)((u + 0x7FFFu + ((u >> 16) & 1u)) >> 16);
}
__device__ __forceinline__ float b2f(ushort_t b) {
    uint_t u = ((uint_t)b) << 16;
    return __builtin_bit_cast(float, u);
}
__device__ __forceinline__ float blo(uint_t u) { return b2f((ushort_t)(u & 0xffffu)); }
__device__ __forceinline__ float bhi(uint_t u) { return b2f((ushort_t)(u >> 16)); }

typedef short bf8 __attribute__((ext_vector_type(8)));
typedef float f4v __attribute__((ext_vector_type(4)));

// ===== all weight transposes in ONE kernel (proven r8) =====
__global__ __launch_bounds__(256) void k_wt_all(
    const float* __restrict__ in_w, const float* __restrict__ inproj_w,
    const float* __restrict__ outproj_w,
    ushort_t* __restrict__ wt_in, ushort_t* __restrict__ wt_inp,
    ushort_t* __restrict__ wt_out)
{
    __shared__ float tile[64][65];
    int idx = blockIdx.x;
    const float* W; ushort_t* Wt; int K, N, k0, n0;
    if (idx < 16) {
        W = in_w; Wt = wt_in; K = 512; N = 128;
        k0 = (idx & 7) * 64; n0 = (idx >> 3) * 64;
    } else if (idx < 52) {
        int r = idx - 16; int l = r / 18; r -= l * 18;
        W = inproj_w + l * 128 * PROJ; Wt = wt_inp + l * 576 * 128; K = 128; N = PROJ;
        k0 = (r & 1) * 64; n0 = (r >> 1) * 64;
    } else {
        int r = idx - 52; int l = r / 8; r -= l * 8;
        W = outproj_w + l * 256 * 128; Wt = wt_out + l * 128 * 256; K = 256; N = 128;
        k0 = (r & 3) * 64; n0 = (r >> 2) * 64;
    }
    const int tid = threadIdx.x;
#pragma unroll
    for (int it = 0; it < 16; ++it) {
        const int e = it * 256 + tid;
        const int kk = e >> 6, nn = e & 63;
        tile[kk][nn] = (n0 + nn < N) ? W[(k0 + kk) * N + (n0 + nn)] : 0.f;
    }
    __syncthreads();
#pragma unroll
    for (int it = 0; it < 16; ++it) {
        const int e = it * 256 + tid;
        const int nn = e >> 6, kk = e & 63;
        Wt[(n0 + nn) * K + k0 + kk] = f2b(tile[kk][nn]);
    }
}

// ===== input GEMM, n-tile PAIRED (r9): A (fp32 x -> bf16 pack) staged ONCE
// per kc-chunk, both 64-col n-tiles consumed before restaging. =====
__global__ __launch_bounds__(256) void k_gemm_in(
    const float* __restrict__ x, const ushort_t* __restrict__ Bt,
    const float* __restrict__ ib, float* __restrict__ C)
{
    __shared__ ushort_t Als[64 * 136];
    __shared__ ushort_t Bls[64 * 136];
    const int m0 = blockIdx.x * 64;
    const int tid = threadIdx.x;
    const int lane = tid & 63, w = tid >> 6;
    const int wm = (w >> 1) * 32, wn = (w & 1) * 32;
    const int r16 = lane & 15, q8 = (lane >> 4) * 8;

    f4v acc[2][2][2];   // [half][i][j]
#pragma unroll
    for (int hf = 0; hf < 2; ++hf)
#pragma unroll
        for (int i = 0; i < 2; ++i)
#pragma unroll
            for (int j = 0; j < 2; ++j) acc[hf][i][j] = (f4v)0.f;

    for (int kc = 0; kc < 512; kc += 128) {
        // A staging + fp32->bf16 pack: once per kc
#pragma unroll
        for (int i = 0; i < 4; ++i) {
            const int e = i * 2048 + tid * 8;
            const int r = e >> 7, c = e & 127;
            const float4 f0 = *(const float4*)&x[(m0 + r) * 512 + kc + c];
            const float4 f1 = *(const float4*)&x[(m0 + r) * 512 + kc + c + 4];
            uint4 pk;
            pk.x = (uint_t)f2b(f0.x) | ((uint_t)f2b(f0.y) << 16);
            pk.y = (uint_t)f2b(f0.z) | ((uint_t)f2b(f0.w) << 16);
            pk.z = (uint_t)f2b(f1.x) | ((uint_t)f2b(f1.y) << 16);
            pk.w = (uint_t)f2b(f1.z) | ((uint_t)f2b(f1.w) << 16);
            *(uint4*)&Als[r * 136 + c] = pk;
        }
#pragma unroll
        for (int hf = 0; hf < 2; ++hf) {
            const int n0 = hf * 64;
#pragma unroll
            for (int i = 0; i < 4; ++i) {
                const int e = i * 2048 + tid * 8;
                const int r = e >> 7, c = e & 127;
                *(uint4*)&Bls[r * 136 + c] = *(const uint4*)&Bt[(n0 + r) * 512 + kc + c];
            }
            __syncthreads();
#pragma unroll
            for (int kk = 0; kk < 128; kk += 32) {
                const bf8 a0 = *(const bf8*)&Als[(wm + r16) * 136 + kk + q8];
                const bf8 a1 = *(const bf8*)&Als[(wm + 16 + r16) * 136 + kk + q8];
                const bf8 b0 = *(const bf8*)&Bls[(wn + r16) * 136 + kk + q8];
                const bf8 b1 = *(const bf8*)&Bls[(wn + 16 + r16) * 136 + kk + q8];
                acc[hf][0][0] = __builtin_amdgcn_mfma_f32_16x16x32_bf16(a0, b0, acc[hf][0][0], 0, 0, 0);
                acc[hf][0][1] = __builtin_amdgcn_mfma_f32_16x16x32_bf16(a0, b1, acc[hf][0][1], 0, 0, 0);
                acc[hf][1][0] = __builtin_amdgcn_mfma_f32_16x16x32_bf16(a1, b0, acc[hf][1][0], 0, 0, 0);
                acc[hf][1][1] = __builtin_amdgcn_mfma_f32_16x16x32_bf16(a1, b1, acc[hf][1][1], 0, 0, 0);
            }
            __syncthreads();
        }
    }
    const int q4 = (lane >> 4) * 4;
#pragma unroll
    for (int hf = 0; hf < 2; ++hf)
#pragma unroll
        for (int i = 0; i < 2; ++i)
#pragma unroll
            for (int j = 0; j < 2; ++j)
#pragma unroll
                for (int r = 0; r < 4; ++r) {
                    const int grow = m0 + wm + i * 16 + q4 + r;
                    const int gcol = hf * 64 + wn + j * 16 + r16;
                    C[grow * 128 + gcol] = acc[hf][i][j][r] + ib[gcol];
                }
}

// ===== inproj GEMM + inline RMSNorm — n-tile TRIPLES (r12): 9 tiles = 3x3,
// A staged+normed once per block, A-redundancy 5 -> 3. LDS/occupancy
// unchanged; per-output bits identical to r9/r11. =====
__global__ __launch_bounds__(256) void k_gemm_rms(
    const float* __restrict__ h, const float* __restrict__ nw,
    const ushort_t* __restrict__ Bt, ushort_t* __restrict__ projb,
    float* __restrict__ dtraw)
{
    __shared__ ushort_t Als[64 * 136];
    __shared__ ushort_t Bls[64 * 136];
    const int m0 = blockIdx.x * 64;
    const int tid = threadIdx.x;
    const int lane = tid & 63, w = tid >> 6;
    const int wm = (w >> 1) * 32, wn = (w & 1) * 32;
    const int r16 = lane & 15, q8 = (lane >> 4) * 8;
    const int q4 = (lane >> 4) * 4;

    // A staging + inline rmsnorm: ONCE per block
#pragma unroll
    for (int i = 0; i < 4; ++i) {
        const int e = i * 2048 + tid * 8;
        const int r = e >> 7, c = e & 127;
        const float4 f0 = *(const float4*)&h[(m0 + r) * 128 + c];
        const float4 f1 = *(const float4*)&h[(m0 + r) * 128 + c + 4];
        float ss = f0.x * f0.x + f0.y * f0.y + f0.z * f0.z + f0.w * f0.w
                 + f1.x * f1.x + f1.y * f1.y + f1.z * f1.z + f1.w * f1.w;
#pragma unroll
        for (int off = 1; off < 16; off <<= 1) ss += __shfl_xor(ss, off);
        const float rs = rsqrtf(ss * (1.f / 128.f) + EPSF);
        const float4 w0 = *(const float4*)&nw[c];
        const float4 w1 = *(const float4*)&nw[c + 4];
        uint4 pk;
        pk.x = (uint_t)f2b(f0.x * rs * w0.x) | ((uint_t)f2b(f0.y * rs * w0.y) << 16);
        pk.y = (uint_t)f2b(f0.z * rs * w0.z) | ((uint_t)f2b(f0.w * rs * w0.w) << 16);
        pk.z = (uint_t)f2b(f1.x * rs * w1.x) | ((uint_t)f2b(f1.y * rs * w1.y) << 16);
        pk.w = (uint_t)f2b(f1.z * rs * w1.z) | ((uint_t)f2b(f1.w * rs * w1.w) << 16);
        *(uint4*)&Als[r * 136 + c] = pk;
    }

#pragma unroll
    for (int third = 0; third < 3; ++third) {
        const int n0 = blockIdx.y * 192 + third * 64;   // covers 0..575 exactly
#pragma unroll
        for (int i = 0; i < 4; ++i) {
            const int e = i * 2048 + tid * 8;
            const int r = e >> 7, c = e & 127;
            *(uint4*)&Bls[r * 136 + c] = *(const uint4*)&Bt[(n0 + r) * 128 + c];
        }
        __syncthreads();

        f4v acc[2][2];
#pragma unroll
        for (int i = 0; i < 2; ++i)
#pragma unroll
            for (int j = 0; j < 2; ++j) acc[i][j] = (f4v)0.f;
#pragma unroll
        for (int kk = 0; kk < 128; kk += 32) {
            const bf8 a0 = *(const bf8*)&Als[(wm + r16) * 136 + kk + q8];
            const bf8 a1 = *(const bf8*)&Als[(wm + 16 + r16) * 136 + kk + q8];
            const bf8 b0 = *(const bf8*)&Bls[(wn + r16) * 136 + kk + q8];
            const bf8 b1 = *(const bf8*)&Bls[(wn + 16 + r16) * 136 + kk + q8];
            acc[0][0] = __builtin_amdgcn_mfma_f32_16x16x32_bf16(a0, b0, acc[0][0], 0, 0, 0);
            acc[0][1] = __builtin_amdgcn_mfma_f32_16x16x32_bf16(a0, b1, acc[0][1], 0, 0, 0);
            acc[1][0] = __builtin_amdgcn_mfma_f32_16x16x32_bf16(a1, b0, acc[1][0], 0, 0, 0);
            acc[1][1] = __builtin_amdgcn_mfma_f32_16x16x32_bf16(a1, b1, acc[1][1], 0, 0, 0);
        }
        __syncthreads();   // protect Bls before restage

#pragma unroll
        for (int i = 0; i < 2; ++i)
#pragma unroll
            for (int j = 0; j < 2; ++j)
#pragma unroll
                for (int r = 0; r < 4; ++r) {
                    const int grow = m0 + wm + i * 16 + q4 + r;
                    const int gcol = n0 + wn + j * 16 + r16;
                    if (gcol < 544) projb[grow * 544 + gcol] = f2b(acc[i][j][r]);
                    else if (gcol < PROJ) dtraw[grow * 4 + (gcol - 544)] = acc[i][j][r];
                }
    }
}

// ===== outproj GEMM + inline gated-RMSNorm — n-tile PAIRED (r9) =====
__global__ __launch_bounds__(256) void k_gemm_gn(
    const ushort_t* __restrict__ yb, const ushort_t* __restrict__ projb,
    const float* __restrict__ gw, const ushort_t* __restrict__ Bt,
    float* __restrict__ C)
{
    __shared__ ushort_t Als[64 * 264];
    __shared__ ushort_t Bls[64 * 136];
    const int m0 = blockIdx.x * 64;
    const int tid = threadIdx.x;
    const int lane = tid & 63, w = tid >> 6;
    const int wm = (w >> 1) * 32, wn = (w & 1) * 32;
    const int r16 = lane & 15, q8 = (lane >> 4) * 8;
    const int q4 = (lane >> 4) * 4;

#pragma unroll
    for (int i = 0; i < 8; ++i) {
        const int e = i * 2048 + tid * 8;
        const int r = e >> 8, c = e & 255;
        const uint4 yv = *(const uint4*)&yb[(m0 + r) * 256 + c];
        const uint4 gv = *(const uint4*)&projb[(m0 + r) * 544 + c];
        const float g0 = blo(gv.x), g1 = bhi(gv.x), g2 = blo(gv.y), g3 = bhi(gv.y);
        const float g4 = blo(gv.z), g5 = bhi(gv.z), g6 = blo(gv.w), g7 = bhi(gv.w);
        float v0 = blo(yv.x) * (g0 / (1.f + __expf(-g0)));
        float v1 = bhi(yv.x) * (g1 / (1.f + __expf(-g1)));
        float v2 = blo(yv.y) * (g2 / (1.f + __expf(-g2)));
        float v3 = bhi(yv.y) * (g3 / (1.f + __expf(-g3)));
        float v4 = blo(yv.z) * (g4 / (1.f + __expf(-g4)));
        float v5 = bhi(yv.z) * (g5 / (1.f + __expf(-g5)));
        float v6 = blo(yv.w) * (g6 / (1.f + __expf(-g6)));
        float v7 = bhi(yv.w) * (g7 / (1.f + __expf(-g7)));
        float ss = v0 * v0 + v1 * v1 + v2 * v2 + v3 * v3
                 + v4 * v4 + v5 * v5 + v6 * v6 + v7 * v7;
#pragma unroll
        for (int off = 1; off < 32; off <<= 1) ss += __shfl_xor(ss, off);
        const float rs = rsqrtf(ss * (1.f / 256.f) + EPSF);
        const float4 w0 = *(const float4*)&gw[c];
        const float4 w1 = *(const float4*)&gw[c + 4];
        uint4 pk;
        pk.x = (uint_t)f2b(v0 * rs * w0.x) | ((uint_t)f2b(v1 * rs * w0.y) << 16);
        pk.y = (uint_t)f2b(v2 * rs * w0.z) | ((uint_t)f2b(v3 * rs * w0.w) << 16);
        pk.z = (uint_t)f2b(v4 * rs * w1.x) | ((uint_t)f2b(v5 * rs * w1.y) << 16);
        pk.w = (uint_t)f2b(v6 * rs * w1.z) | ((uint_t)f2b(v7 * rs * w1.w) << 16);
        *(uint4*)&Als[r * 264 + c] = pk;
    }

#pragma unroll
    for (int half = 0; half < 2; ++half) {
        const int n0 = half * 64;
        f4v acc[2][2];
#pragma unroll
        for (int i = 0; i < 2; ++i)
#pragma unroll
            for (int j = 0; j < 2; ++j) acc[i][j] = (f4v)0.f;

        for (int kc = 0; kc < 256; kc += 128) {
#pragma unroll
            for (int i = 0; i < 4; ++i) {
                const int e = i * 2048 + tid * 8;
                const int r = e >> 7, c = e & 127;
                *(uint4*)&Bls[r * 136 + c] = *(const uint4*)&Bt[(n0 + r) * 256 + kc + c];
            }
            __syncthreads();
#pragma unroll
            for (int kk = 0; kk < 128; kk += 32) {
                const bf8 a0 = *(const bf8*)&Als[(wm + r16) * 264 + kc + kk + q8];
                const bf8 a1 = *(const bf8*)&Als[(wm + 16 + r16) * 264 + kc + kk + q8];
                const bf8 b0 = *(const bf8*)&Bls[(wn + r16) * 136 + kk + q8];
                const bf8 b1 = *(const bf8*)&Bls[(wn + 16 + r16) * 136 + kk + q8];
                acc[0][0] = __builtin_amdgcn_mfma_f32_16x16x32_bf16(a0, b0, acc[0][0], 0, 0, 0);
                acc[0][1] = __builtin_amdgcn_mfma_f32_16x16x32_bf16(a0, b1, acc[0][1], 0, 0, 0);
                acc[1][0] = __builtin_amdgcn_mfma_f32_16x16x32_bf16(a1, b0, acc[1][0], 0, 0, 0);
                acc[1][1] = __builtin_amdgcn_mfma_f32_16x16x32_bf16(a1, b1, acc[1][1], 0, 0, 0);
            }
            __syncthreads();
        }

#pragma unroll
        for (int i = 0; i < 2; ++i)
#pragma unroll
            for (int j = 0; j < 2; ++j)
#pragma unroll
                for (int r = 0; r < 4; ++r) {
                    const int grow = m0 + wm + i * 16 + q4 + r;
                    const int gcol = n0 + wn + j * 16 + r16;
                    C[grow * 128 + gcol] += acc[i][j][r];
                }
    }
}

// dtprep scan, wave-0-only, bit-identical to the Hillis-Steele ladder (r7)
__device__ __forceinline__ void dt_scan_wave0(
    const float* __restrict__ dtraw, const float* __restrict__ A_log,
    const float* __restrict__ dt_bias, int l, int hh, int m0, int lane,
    float* __restrict__ cumls, float* __restrict__ dtls)
{
    const float Ah = -expf(A_log[l * NH + hh]);
    const float bias = dt_bias[l * NH + hh];
    const float r0 = dtraw[(m0 + lane) * 4 + hh] + bias;
    const float r1 = dtraw[(m0 + 64 + lane) * 4 + hh] + bias;
    const float dt0 = (r0 > 20.f) ? r0 : log1pf(expf(r0));
    const float dt1 = (r1 > 20.f) ? r1 : log1pf(expf(r1));
    float v0 = dt0 * Ah, v1 = dt1 * Ah;
#pragma unroll
    for (int off = 1; off < 64; off <<= 1) {
        const int src = (lane - off) & 63;
        const float s0 = __shfl(v0, src);
        const float s1 = __shfl(v1, src);
        v0 += (lane >= off) ? s0 : 0.f;
        v1 += (lane >= off) ? s1 : s0;   // cross-half term for lane<off
    }
    v1 += v0;                             // off = 64 step
    cumls[lane] = v0; cumls[64 + lane] = v1;
    dtls[lane]  = dt0; dtls[64 + lane]  = dt1;
}

// ===== fused conv+dtprep+SSD-chunk-state (r9 proven, c==15 early exit) =====
__global__ __launch_bounds__(256) void k_ssd_state(
    const ushort_t* __restrict__ projb, const float* __restrict__ dtraw,
    const float* __restrict__ cw, const float* __restrict__ cb,
    const float* __restrict__ A_log, const float* __restrict__ dt_bias,
    float* __restrict__ zbuf, float* __restrict__ dec, int l)
{
    __shared__ ushort_t Xt[64 * 136];
    __shared__ ushort_t wB[16 * 136];
    __shared__ ushort_t pX[131 * 64];
    __shared__ ushort_t pB[131 * 16];
    __shared__ float cumls[QCH];
    __shared__ float dtls[QCH];
    const int bid = blockIdx.x;
    const int c = bid & (NC - 1);
    if (c == NC - 1) return;   // dead work: prefix uses only cc < c
    const int hh = (bid / NC) & (NH - 1);
    const int b = bid / (NC * NH);
    const int m0 = b * T_ + c * QCH;
    const int tid = threadIdx.x;
    const int lane = tid & 63;

    if (tid < 64) {
        dt_scan_wave0(dtraw, A_log, dt_bias, l, hh, m0, lane, cumls, dtls);
    } else {
        const int t0 = c * QCH;
        for (int e = tid - 64; e < 131 * 8; e += 192) {
            const int ls = e >> 3, j = e & 7;
            const int tb = t0 + ls - 3;
            uint4 v; v.x = 0u; v.y = 0u; v.z = 0u; v.w = 0u;
            if (tb >= 0) v = *(const uint4*)&projb[(b * T_ + tb) * 544 + 256 + hh * 64 + j * 8];
            *(uint4*)&pX[ls * 64 + j * 8] = v;
        }
        for (int e = tid - 64; e < 131 * 2; e += 192) {
            const int ls = e >> 1, j = e & 1;
            const int tb = t0 + ls - 3;
            uint4 v; v.x = 0u; v.y = 0u; v.z = 0u; v.w = 0u;
            if (tb >= 0) v = *(const uint4*)&projb[(b * T_ + tb) * 544 + 512 + j * 8];
            *(uint4*)&pB[ls * 16 + j * 8] = v;
        }
    }
    __syncthreads();
    const float clast = cumls[QCH - 1];

    {
        const int p = tid & 63;
        const int s0 = tid >> 6;
        const float* wp = cw + (l * CONVDIM + hh * 64 + p) * KCONV;
        const float bbv = cb[l * CONVDIM + hh * 64 + p];
#pragma unroll
        for (int pass = 0; pass < 32; ++pass) {
            const int s = pass * 4 + s0;
            float a = bbv;
#pragma unroll
            for (int k = 0; k < KCONV; ++k) a += b2f(pX[(s + k) * 64 + p]) * wp[k];
            Xt[p * 136 + s] = f2b(a / (1.f + __expf(-a)));
        }
    }
    {
        const int n = tid & 15;
        const int s0 = tid >> 4;
        const float* wp = cw + (l * CONVDIM + 256 + n) * KCONV;
        const float bbv = cb[l * CONVDIM + 256 + n];
#pragma unroll
        for (int pass = 0; pass < 8; ++pass) {
            const int s = pass * 16 + s0;
            float a = bbv;
#pragma unroll
            for (int k = 0; k < KCONV; ++k) a += b2f(pB[(s + k) * 16 + n]) * wp[k];
            const ushort_t sb = f2b(a / (1.f + __expf(-a)));
            const float w = __expf(clast - cumls[s]) * dtls[s];
            wB[n * 136 + s] = f2b(w * b2f(sb));
        }
    }
    __syncthreads();

    const int w = tid >> 6;
    const int r16 = lane & 15, q8 = (lane >> 4) * 8, q4 = (lane >> 4) * 4;
    f4v acc = (f4v)0.f;
#pragma unroll
    for (int kc = 0; kc < 128; kc += 32) {
        const bf8 a = *(const bf8*)&Xt[(w * 16 + r16) * 136 + kc + q8];
        const bf8 bb = *(const bf8*)&wB[r16 * 136 + kc + q8];
        acc = __builtin_amdgcn_mfma_f32_16x16x32_bf16(a, bb, acc, 0, 0, 0);
    }
#pragma unroll
    for (int r = 0; r < 4; ++r) {
        const int p = w * 16 + q4 + r;
        zbuf[bid * 1024 + p * 16 + r16] = acc[r];
    }
    if (tid == 0) dec[bid] = __expf(clast);
}

// ===== fused conv+dtprep+SSD-y (r7 proven) =====
__global__ __launch_bounds__(256) void k_ssd_y(
    const ushort_t* __restrict__ projb, const float* __restrict__ dtraw,
    const float* __restrict__ cw, const float* __restrict__ cb,
    const float* __restrict__ A_log, const float* __restrict__ dt_bias,
    const float* __restrict__ zbuf, const float* __restrict__ dec,
    const float* __restrict__ Dvec, ushort_t* __restrict__ yb, int l)
{
    __shared__ ushort_t Xt[64 * 136];
    __shared__ ushort_t BlsT[128 * 40];
    __shared__ ushort_t ClsT[128 * 40];
    __shared__ ushort_t Gls[128 * 136];   // staging alias: pX | pB | pC during conv
    __shared__ ushort_t Spt[64 * 40];
    __shared__ float cumls[QCH];
    __shared__ float dtls[QCH];
    ushort_t* pX = Gls;                    // 131*64 = 8384
    ushort_t* pB = Gls + 131 * 64;         // 131*16 = 2096
    ushort_t* pC = Gls + 131 * 64 + 131 * 16;
    const int bid = blockIdx.x;
    const int c = bid & (NC - 1);
    const int hh = (bid / NC) & (NH - 1);
    const int b = bid / (NC * NH);
    const int bh = bid >> 4;               // b*NH + hh (NC==16)
    const int m0 = b * T_ + c * QCH;
    const int tid = threadIdx.x;
    const int lane = tid & 63;

    if (tid < 64) {
        dt_scan_wave0(dtraw, A_log, dt_bias, l, hh, m0, lane, cumls, dtls);
    } else {
        const int t0 = c * QCH;
        for (int e = tid - 64; e < 131 * 8; e += 192) {
            const int ls = e >> 3, j = e & 7;
            const int tb = t0 + ls - 3;
            uint4 v; v.x = 0u; v.y = 0u; v.z = 0u; v.w = 0u;
            if (tb >= 0) v = *(const uint4*)&projb[(b * T_ + tb) * 544 + 256 + hh * 64 + j * 8];
            *(uint4*)&pX[ls * 64 + j * 8] = v;
        }
        for (int e = tid - 64; e < 131 * 2; e += 192) {
            const int ls = e >> 1, j = e & 1;
            const int tb = t0 + ls - 3;
            uint4 v0; v0.x = 0u; v0.y = 0u; v0.z = 0u; v0.w = 0u;
            uint4 v1 = v0;
            if (tb >= 0) {
                v0 = *(const uint4*)&projb[(b * T_ + tb) * 544 + 512 + j * 8];
                v1 = *(const uint4*)&projb[(b * T_ + tb) * 544 + 528 + j * 8];
            }
            *(uint4*)&pB[ls * 16 + j * 8] = v0;
            *(uint4*)&pC[ls * 16 + j * 8] = v1;
        }
    }
    __syncthreads();

    {
        const int p = tid & 63;
        const int s0 = tid >> 6;
        const float* wp = cw + (l * CONVDIM + hh * 64 + p) * KCONV;
        const float bbv = cb[l * CONVDIM + hh * 64 + p];
#pragma unroll
        for (int pass = 0; pass < 32; ++pass) {
            const int s = pass * 4 + s0;
            float a = bbv;
#pragma unroll
            for (int k = 0; k < KCONV; ++k) a += b2f(pX[(s + k) * 64 + p]) * wp[k];
            Xt[p * 136 + s] = f2b(a / (1.f + __expf(-a)));
        }
    }
    {
        const int n = tid & 15;
        const int s0 = tid >> 4;
        const float* wpB = cw + (l * CONVDIM + 256 + n) * KCONV;
        const float bbB = cb[l * CONVDIM + 256 + n];
        const float* wpC = cw + (l * CONVDIM + 272 + n) * KCONV;
        const float bbC = cb[l * CONVDIM + 272 + n];
#pragma unroll
        for (int pass = 0; pass < 8; ++pass) {
            const int s = pass * 16 + s0;
            float aB = bbB, aC = bbC;
#pragma unroll
            for (int k = 0; k < KCONV; ++k) {
                aB += b2f(pB[(s + k) * 16 + n]) * wpB[k];
                aC += b2f(pC[(s + k) * 16 + n]) * wpC[k];
            }
            BlsT[s * 40 + n] = f2b(aB / (1.f + __expf(-aB)));
            ClsT[s * 40 + n] = f2b(aC / (1.f + __expf(-aC)));
            BlsT[s * 40 + 16 + n] = 0;
            ClsT[s * 40 + 16 + n] = 0;
        }
    }
    {
        float4 S; S.x = 0.f; S.y = 0.f; S.z = 0.f; S.w = 0.f;
        for (int cc = 0; cc < c; ++cc) {
            const float d = dec[bh * NC + cc];
            const float4 z = *(const float4*)(zbuf + (bh * NC + cc) * 1024 + tid * 4);
            S.x = S.x * d + z.x; S.y = S.y * d + z.y;
            S.z = S.z * d + z.z; S.w = S.w * d + z.w;
        }
        const int p = tid >> 2, n = (tid & 3) * 4;
        Spt[p * 40 + n]     = f2b(S.x);
        Spt[p * 40 + n + 1] = f2b(S.y);
        Spt[p * 40 + n + 2] = f2b(S.z);
        Spt[p * 40 + n + 3] = f2b(S.w);
        Spt[p * 40 + 16 + n]     = 0;
        Spt[p * 40 + 16 + n + 1] = 0;
        Spt[p * 40 + 16 + n + 2] = 0;
        Spt[p * 40 + 16 + n + 3] = 0;
    }
    __syncthreads();   // conv + scan done; praw (Gls alias) now dead

    const int w = tid >> 6;
    const int wrow = w * 32;
    const int r16 = lane & 15, q8 = (lane >> 4) * 8, q4 = (lane >> 4) * 4;
    const float Dh = Dvec[l * NH + hh];

    bf8 cfr[2];
#pragma unroll
    for (int i = 0; i < 2; ++i)
        cfr[i] = *(const bf8*)&ClsT[(wrow + i * 16 + r16) * 40 + q8];

    float cumt[8], et[8];
#pragma unroll
    for (int i = 0; i < 2; ++i)
#pragma unroll
        for (int r = 0; r < 4; ++r) {
            const int t = wrow + i * 16 + q4 + r;
            cumt[i * 4 + r] = cumls[t];
            et[i * 4 + r] = __expf(cumls[t]);
        }

    f4v acc[2][4];
#pragma unroll
    for (int j = 0; j < 4; ++j) {
        const bf8 sf = *(const bf8*)&Spt[(j * 16 + r16) * 40 + q8];
#pragma unroll
        for (int i = 0; i < 2; ++i) {
            f4v z = (f4v)0.f;
            z = __builtin_amdgcn_mfma_f32_16x16x32_bf16(cfr[i], sf, z, 0, 0, 0);
#pragma unroll
            for (int r = 0; r < 4; ++r) {
                const int t = wrow + i * 16 + q4 + r;
                const int p = j * 16 + r16;
                acc[i][j][r] = z[r] * et[i * 4 + r] + Dh * b2f(Xt[p * 136 + t]);
            }
        }
    }

#pragma unroll
    for (int ts = 0; ts < 8; ++ts) {
        const bf8 bf = *(const bf8*)&BlsT[(ts * 16 + r16) * 40 + q8];
        const int s = ts * 16 + r16;
        const float cs = cumls[s];
        const float ds = dtls[s];
#pragma unroll
        for (int i = 0; i < 2; ++i) {
            f4v g = (f4v)0.f;
            g = __builtin_amdgcn_mfma_f32_16x16x32_bf16(cfr[i], bf, g, 0, 0, 0);
#pragma unroll
            for (int r = 0; r < 4; ++r) {
                const int t = wrow + i * 16 + q4 + r;
                const float val = (s <= t) ? __expf(cumt[i * 4 + r] - cs) * ds * g[r] : 0.f;
                Gls[t * 136 + s] = f2b(val);
            }
        }
    }
    __syncthreads();

#pragma unroll
    for (int kc = 0; kc < 128; kc += 32) {
        bf8 af[2];
#pragma unroll
        for (int i = 0; i < 2; ++i)
            af[i] = *(const bf8*)&Gls[(wrow + i * 16 + r16) * 136 + kc + q8];
#pragma unroll
        for (int j = 0; j < 4; ++j) {
            const bf8 xf = *(const bf8*)&Xt[(j * 16 + r16) * 136 + kc + q8];
#pragma unroll
            for (int i = 0; i < 2; ++i)
                acc[i][j] = __builtin_amdgcn_mfma_f32_16x16x32_bf16(af[i], xf, acc[i][j], 0, 0, 0);
        }
    }

#pragma unroll
    for (int i = 0; i < 2; ++i)
#pragma unroll
        for (int r = 0; r < 4; ++r) {
            const int t = wrow + i * 16 + q4 + r;
#pragma unroll
            for (int j = 0; j < 4; ++j) {
                const int p = j * 16 + r16;
                yb[(m0 + t) * DINNER + hh * 64 + p] = f2b(acc[i][j][r]);
            }
        }
}

// ===== final rmsnorm + partial mean-pool (proven) =====
__global__ __launch_bounds__(256) void k_finalnorm_pool(
    const float* __restrict__ h, const float* __restrict__ nfw,
    float* __restrict__ part)
{
    __shared__ float ht[2048];
    __shared__ float red[256];
    __shared__ float rstd[16];
    __shared__ float padd[256];
    const int tile = blockIdx.x & 127;
    const int b = blockIdx.x >> 7;
    const int m0 = b * T_ + tile * 16;
    const int tid = threadIdx.x;
    for (int e = tid; e < 2048; e += 256) ht[e] = h[m0 * DM + e];
    __syncthreads();
    {
        const int tg = tid >> 4, j0 = tid & 15;
        float p = 0.f;
#pragma unroll
        for (int k = 0; k < 8; ++k) { const float v = ht[tg * 128 + j0 + 16 * k]; p += v * v; }
        red[tid] = p;
    }
    __syncthreads();
    if (tid < 16) {
        float s = 0.f;
#pragma unroll
        for (int q = 0; q < 16; ++q) s += red[tid * 16 + q];
        rstd[tid] = rsqrtf(s * (1.f / 128.f) + EPSF);
    }
    __syncthreads();
    const int d = tid & 127, half = tid >> 7;
    float ps = 0.f;
#pragma unroll
    for (int i0 = 0; i0 < 8; ++i0) { const int i = half + 2 * i0; ps += ht[i * 128 + d] * rstd[i]; }
    padd[tid] = ps;
    __syncthreads();
    if (tid < 128) part[(b * 128 + tile) * 128 + tid] = (padd[tid] + padd[128 + tid]) * nfw[tid];
}

// ===== pooled reduce + head GEMM — output-split 4x (r12).
// Each (b, oy) block recomputes pooled[128] with the EXACT serial tile order
// (bit-identical) and emits outputs [oy*128, oy*128+128). 8 -> 32 blocks.
__global__ __launch_bounds__(256) void k_head(
    const float* __restrict__ part, const float* __restrict__ ow,
    const float* __restrict__ ob, float* __restrict__ out)
{
    __shared__ float pooled[128];
    const int b = blockIdx.x;
    const int o0 = blockIdx.y * 128;
    const int tid = threadIdx.x;
    if (tid < 128) {
        float s = 0.f;
        for (int tile = 0; tile < 128; ++tile) s += part[(b * 128 + tile) * 128 + tid];
        pooled[tid] = s * (1.f / (float)T_);
    }
    __syncthreads();
    for (int o = o0 + tid; o < o0 + 128; o += 256) {
        float acc = ob[o];
#pragma unroll 4
        for (int d = 0; d < 128; ++d) acc += pooled[d] * ow[d * DIMX + o];
        out[b * DIMX + o] = acc;
    }
}

extern "C" void kernel_launch(void* const* d_in, const int* in_sizes, int n_in,
                              void* d_out, int out_size, void* d_ws, size_t ws_size,
                              hipStream_t stream)
{
    const float* x         = (const float*)d_in[0];
    const float* in_w      = (const float*)d_in[1];
    const float* in_b      = (const float*)d_in[2];
    const float* norm_w    = (const float*)d_in[3];
    const float* inproj_w  = (const float*)d_in[4];
    const float* conv_w    = (const float*)d_in[5];
    const float* conv_b    = (const float*)d_in[6];
    const float* A_log     = (const float*)d_in[7];
    const float* Dvec      = (const float*)d_in[8];
    const float* dt_bias   = (const float*)d_in[9];
    const float* gnorm_w   = (const float*)d_in[10];
    const float* outproj_w = (const float*)d_in[11];
    const float* normf_w   = (const float*)d_in[12];
    const float* out_w     = (const float*)d_in[13];
    const float* out_b     = (const float*)d_in[14];

    float* ws    = (float*)d_ws;
    float* h     = ws + OFF_H;
    float* zbuf  = ws + OFF_Z;
    float* dec   = ws + OFF_DEC;
    float* part  = ws + OFF_PART;
    float* dtraw = ws + OFF_DTRAW;
    ushort_t* projb = (ushort_t*)(ws + OFF_PROJB);
    ushort_t* yb    = (ushort_t*)(ws + OFF_YB);
    ushort_t* wt_in  = (ushort_t*)(ws + OFF_WTIN);
    ushort_t* wt_inp = (ushort_t*)(ws + OFF_WTINP);
    ushort_t* wt_out = (ushort_t*)(ws + OFF_WTOUT);

    k_wt_all<<<68, 256, 0, stream>>>(in_w, inproj_w, outproj_w, wt_in, wt_inp, wt_out);

    k_gemm_in<<<MTOK / 64, 256, 0, stream>>>(x, wt_in, in_b, h);

    for (int l = 0; l < LLAYERS; ++l) {
        k_gemm_rms<<<dim3(MTOK / 64, 3), 256, 0, stream>>>(
            h, norm_w + l * DM, wt_inp + l * 576 * 128, projb, dtraw);
        k_ssd_state<<<B_ * NH * NC, 256, 0, stream>>>(
            projb, dtraw, conv_w, conv_b, A_log, dt_bias, zbuf, dec, l);
        k_ssd_y<<<B_ * NH * NC, 256, 0, stream>>>(
            projb, dtraw, conv_w, conv_b, A_log, dt_bias, zbuf, dec, Dvec, yb, l);
        k_gemm_gn<<<MTOK / 64, 256, 0, stream>>>(
            yb, projb, gnorm_w + l * DINNER, wt_out + l * 128 * 256, h);
    }

    k_finalnorm_pool<<<B_ * (T_ / 16), 256, 0, stream>>>(h, normf_w, part);
    k_head<<<dim3(B_, 4), 256, 0, stream>>>(part, out_w, out_b, (float*)d_out);
}